// Round 1
// baseline (417.804 us; speedup 1.0000x reference)
//
#include <hip/hip_runtime.h>

#define NN 50000
#define NE 800000
#define EN 850000

static constexpr float BN_SC = 0.99999500003749968f; // 1/sqrt(1+1e-5)

__device__ __forceinline__ float4 ld4(const float* p){ return *reinterpret_cast<const float4*>(p); }
__device__ __forceinline__ void st4(float* p, float4 v){ *reinterpret_cast<float4*>(p) = v; }

extern "C" __global__ void k_init_cnt(int* __restrict__ cnt){
  int i = blockIdx.x*256 + threadIdx.x;
  if (i < NN) cnt[i] = 1;                 // self-loop
}

extern "C" __global__ void k_count(const int* __restrict__ ei, int* __restrict__ cnt){
  int e = blockIdx.x*256 + threadIdx.x;
  if (e < NE) atomicAdd(&cnt[ei[NE + e]], 1);   // dst row of edge_index
}

extern "C" __global__ void k_dis(const int* __restrict__ cnt, float* __restrict__ dis){
  int i = blockIdx.x*256 + threadIdx.x;
  if (i < NN) dis[i] = rsqrtf((float)cnt[i]);
}

// ---- 3-kernel exclusive scan of cnt -> offs (1024 elems / block) ----
extern "C" __global__ void k_scan_blocks(const int* __restrict__ cnt, int* __restrict__ offs,
                                         int* __restrict__ bsums){
  __shared__ int lds[256];
  int t = threadIdx.x, b = blockIdx.x;
  int base = b*1024 + t*4;
  int v0 = (base+0 < NN) ? cnt[base+0] : 0;
  int v1 = (base+1 < NN) ? cnt[base+1] : 0;
  int v2 = (base+2 < NN) ? cnt[base+2] : 0;
  int v3 = (base+3 < NN) ? cnt[base+3] : 0;
  int s = v0+v1+v2+v3;
  lds[t] = s;
  __syncthreads();
  int acc = s;
  #pragma unroll
  for (int off = 1; off < 256; off <<= 1){
    int x = (t >= off) ? lds[t-off] : 0;
    __syncthreads();
    acc += x;
    lds[t] = acc;
    __syncthreads();
  }
  int p = acc - s;  // exclusive prefix within block
  if (base+0 < NN) offs[base+0] = p;
  if (base+1 < NN) offs[base+1] = p + v0;
  if (base+2 < NN) offs[base+2] = p + v0 + v1;
  if (base+3 < NN) offs[base+3] = p + v0 + v1 + v2;
  if (t == 255) bsums[b] = acc;
}

extern "C" __global__ void k_scan_bsums(int* __restrict__ bsums){
  __shared__ int lds[64];
  int t = threadIdx.x;
  lds[t] = (t < 49) ? bsums[t] : 0;
  __syncthreads();
  if (t == 0){
    int run = 0;
    for (int i = 0; i < 49; ++i){ int x = lds[i]; lds[i] = run; run += x; }
  }
  __syncthreads();
  if (t < 49) bsums[t] = lds[t];
}

extern "C" __global__ void k_finalize(int* __restrict__ offs, const int* __restrict__ bsums,
                                      int* __restrict__ cursor){
  int i = blockIdx.x*256 + threadIdx.x;
  if (i < NN){ int v = offs[i] + bsums[i >> 10]; offs[i] = v; cursor[i] = v; }
}

extern "C" __global__ void k_fill(const int* __restrict__ ei, const float* __restrict__ dis,
                                  int* __restrict__ cursor, int* __restrict__ csr_s,
                                  float* __restrict__ csr_n){
  int e = blockIdx.x*256 + threadIdx.x;
  if (e >= EN) return;
  int s, d;
  if (e < NE){ s = ei[e]; d = ei[NE + e]; } else { s = e - NE; d = s; }
  float nv = dis[s]*dis[d];
  int pos = atomicAdd(&cursor[d], 1);
  csr_s[pos] = s;
  csr_n[pos] = nv;
}

// Wt[k][f] = W[f][k]
extern "C" __global__ void k_transpose(const float* __restrict__ W, float* __restrict__ Wt){
  int idx = blockIdx.x*256 + threadIdx.x;
  int f = idx >> 7, k = idx & 127;
  Wt[k*128 + f] = W[f*128 + k];
}

// WCt[k][f] = (Ww @ cw)[f][k]  (combined conv+W weight, stored k-major)
extern "C" __global__ void k_combine_wc(const float* __restrict__ Ww, const float* __restrict__ cw,
                                        float* __restrict__ WCt){
  int idx = blockIdx.x*256 + threadIdx.x;
  int f = idx >> 7, k = idx & 127;
  float acc = 0.f;
  #pragma unroll 4
  for (int j = 0; j < 128; ++j) acc = fmaf(Ww[f*128 + j], cw[j*128 + k], acc);
  WCt[k*128 + f] = acc;
}

// WfT[k][c] = (out_w @ fc_out_w)[c][k];  bf[c] = out_b[c] + sum_j out_w[c][j]*fc_out_b[j]
extern "C" __global__ void k_combine_final(const float* __restrict__ ow, const float* __restrict__ fw,
                                           const float* __restrict__ fb, const float* __restrict__ ob,
                                           float* __restrict__ WfT, float* __restrict__ bf){
  int idx = blockIdx.x*256 + threadIdx.x;
  if (idx < 5120){
    int c = idx >> 7, k = idx & 127;
    float acc = 0.f;
    for (int j = 0; j < 128; ++j) acc = fmaf(ow[c*128 + j], fw[j*128 + k], acc);
    WfT[k*40 + c] = acc;
  }
  if (idx < 40){
    float acc = ob[idx];
    for (int j = 0; j < 128; ++j) acc = fmaf(ow[idx*128 + j], fb[j], acc);
    bf[idx] = acc;
  }
}

// Agg[n] = sum_{e in CSR[n]} norm_e * Hf[src_e]   -- one wave per node, 2 edges/iter
extern "C" __global__ __launch_bounds__(256)
void k_gather(const float* __restrict__ Hf, const int* __restrict__ csr_s,
              const float* __restrict__ csr_n, const int* __restrict__ offs,
              const int* __restrict__ cnt, float* __restrict__ Agg){
  int lane = threadIdx.x & 63;
  int node = blockIdx.x*4 + (threadIdx.x >> 6);
  int half = lane >> 5;
  int q4 = (lane & 31)*4;
  int start = offs[node];
  int n = cnt[node];
  float ax = 0.f, ay = 0.f, az = 0.f, aw = 0.f;
  for (int k = half; k < n; k += 2){
    int e = start + k;
    int s = csr_s[e];
    float nv = csr_n[e];
    float4 v = ld4(Hf + s*128 + q4);
    ax = fmaf(v.x, nv, ax); ay = fmaf(v.y, nv, ay);
    az = fmaf(v.z, nv, az); aw = fmaf(v.w, nv, aw);
  }
  ax += __shfl_xor(ax, 32); ay += __shfl_xor(ay, 32);
  az += __shfl_xor(az, 32); aw += __shfl_xor(aw, 32);
  if (half == 0){
    float4 o; o.x = ax; o.y = ay; o.z = az; o.w = aw;
    st4(Agg + node*128 + q4, o);
  }
}

// C = relu(bn((X @ W^T) + bias));  MODE 1: Jk = C;  MODE 2: Jk = max(Jk, C).
// Wt is W pre-transposed [k][f]. BM=128 rows/block, 512 threads, 8x4 acc/thread.
// X rows are read straight from global as in-wave broadcasts (each row read once/block).
template<int MODE>
__global__ __launch_bounds__(512, 4)
void k_gemm(const float* __restrict__ X, const float* __restrict__ Wt,
            const float* __restrict__ bias, const float* __restrict__ gamma,
            const float* __restrict__ beta, float* __restrict__ Cout,
            float* __restrict__ Jk){
  __shared__ float Bs[128][128];
  const int t = threadIdx.x;
  {
    const float4* src = reinterpret_cast<const float4*>(Wt);
    float4* dst = reinterpret_cast<float4*>(&Bs[0][0]);
    #pragma unroll
    for (int it = 0; it < 8; ++it) dst[it*512 + t] = src[it*512 + t];
  }
  __syncthreads();
  const int c4 = (t & 31)*4;
  const int tr = t >> 5;
  const int m0 = blockIdx.x*128 + tr*4;
  int off[8];
  #pragma unroll
  for (int r = 0; r < 8; ++r){
    int m = m0 + (r & 3) + (r >> 2)*64;
    off[r] = (m < NN ? m : 0)*128;   // clamp OOB rows; store is guarded below
  }
  float acc[8][4] = {};
  for (int kk = 0; kk < 128; kk += 4){
    float b[4][4];
    #pragma unroll
    for (int j = 0; j < 4; ++j){
      float4 v = ld4(&Bs[kk+j][c4]);
      b[j][0] = v.x; b[j][1] = v.y; b[j][2] = v.z; b[j][3] = v.w;
    }
    #pragma unroll
    for (int r = 0; r < 8; ++r){
      float4 v = ld4(X + off[r] + kk);
      #pragma unroll
      for (int q = 0; q < 4; ++q){
        acc[r][q] = fmaf(v.x, b[0][q], acc[r][q]);
        acc[r][q] = fmaf(v.y, b[1][q], acc[r][q]);
        acc[r][q] = fmaf(v.z, b[2][q], acc[r][q]);
        acc[r][q] = fmaf(v.w, b[3][q], acc[r][q]);
      }
    }
  }
  float4 bi = ld4(bias + c4);
  float4 g  = ld4(gamma + c4);
  float4 be = ld4(beta + c4);
  float sc0 = g.x*BN_SC, sc1 = g.y*BN_SC, sc2 = g.z*BN_SC, sc3 = g.w*BN_SC;
  #pragma unroll
  for (int r = 0; r < 8; ++r){
    int m = m0 + (r & 3) + (r >> 2)*64;
    if (m < NN){
      float4 o;
      o.x = fmaxf(fmaf(acc[r][0] + bi.x, sc0, be.x), 0.f);
      o.y = fmaxf(fmaf(acc[r][1] + bi.y, sc1, be.y), 0.f);
      o.z = fmaxf(fmaf(acc[r][2] + bi.z, sc2, be.z), 0.f);
      o.w = fmaxf(fmaf(acc[r][3] + bi.w, sc3, be.w), 0.f);
      if (MODE == 1){
        st4(Cout + m*128 + c4, o);
        st4(Jk + m*128 + c4, o);
      } else {
        float4 jo = ld4(Jk + m*128 + c4);
        float4 nj;
        nj.x = fmaxf(jo.x, o.x); nj.y = fmaxf(jo.y, o.y);
        nj.z = fmaxf(jo.z, o.z); nj.w = fmaxf(jo.w, o.w);
        st4(Cout + m*128 + c4, o);
        st4(Jk + m*128 + c4, nj);
      }
    }
  }
}

// Out[m][c] = X[m] . WfT[:][c] + bf[c]   (N=40), BM=128, 128 threads, 8x5 acc
__global__ __launch_bounds__(128)
void k_gemm_final(const float* __restrict__ X, const float* __restrict__ WfT,
                  const float* __restrict__ bf, float* __restrict__ Out){
  __shared__ float Bs[5120];
  const int t = threadIdx.x;
  #pragma unroll
  for (int it = 0; it < 40; ++it) Bs[it*128 + t] = WfT[it*128 + t];
  __syncthreads();
  const int cg = (t & 7)*5;
  const int tr = t >> 3;
  const int m0 = blockIdx.x*128 + tr*4;
  int off[8];
  #pragma unroll
  for (int r = 0; r < 8; ++r){
    int m = m0 + (r & 3) + (r >> 2)*64;
    off[r] = (m < NN ? m : 0)*128;
  }
  float acc[8][5] = {};
  for (int kk = 0; kk < 128; kk += 4){
    float b[4][5];
    #pragma unroll
    for (int j = 0; j < 4; ++j)
      #pragma unroll
      for (int q = 0; q < 5; ++q)
        b[j][q] = Bs[(kk+j)*40 + cg + q];
    #pragma unroll
    for (int r = 0; r < 8; ++r){
      float4 v = ld4(X + off[r] + kk);
      #pragma unroll
      for (int q = 0; q < 5; ++q){
        acc[r][q] = fmaf(v.x, b[0][q], acc[r][q]);
        acc[r][q] = fmaf(v.y, b[1][q], acc[r][q]);
        acc[r][q] = fmaf(v.z, b[2][q], acc[r][q]);
        acc[r][q] = fmaf(v.w, b[3][q], acc[r][q]);
      }
    }
  }
  float bb[5];
  #pragma unroll
  for (int q = 0; q < 5; ++q) bb[q] = bf[cg + q];
  #pragma unroll
  for (int r = 0; r < 8; ++r){
    int m = m0 + (r & 3) + (r >> 2)*64;
    if (m < NN){
      #pragma unroll
      for (int q = 0; q < 5; ++q) Out[m*40 + cg + q] = acc[r][q] + bb[q];
    }
  }
}

extern "C" void kernel_launch(void* const* d_in, const int* in_sizes, int n_in,
                              void* d_out, int out_size, void* d_ws, size_t ws_size,
                              hipStream_t stream){
  const float* x     = (const float*)d_in[0];
  const int*   ei    = (const int*)d_in[1];
  const float* fc0_w = (const float*)d_in[2];
  const float* fc0_b = (const float*)d_in[3];
  const float* convw = (const float*)d_in[4];
  const float* Ww    = (const float*)d_in[5];
  const float* Wb    = (const float*)d_in[6];
  const float* bng   = (const float*)d_in[7];
  const float* bnb   = (const float*)d_in[8];
  const float* fow   = (const float*)d_in[9];
  const float* fob   = (const float*)d_in[10];
  const float* outw  = (const float*)d_in[11];
  const float* outb  = (const float*)d_in[12];
  float* out = (float*)d_out;

  char* p = (char*)d_ws;
  auto alloc = [&](size_t n){ char* r = p; p += (n + 255) & ~(size_t)255; return r; };
  int*   cnt    = (int*)  alloc((size_t)NN*4);
  int*   offs   = (int*)  alloc((size_t)NN*4);
  int*   cursor = (int*)  alloc((size_t)NN*4);
  float* dis    = (float*)alloc((size_t)NN*4);
  int*   bsums  = (int*)  alloc(64*4);
  int*   csr_s  = (int*)  alloc((size_t)EN*4);
  float* csr_n  = (float*)alloc((size_t)EN*4);
  float* Wt0    = (float*)alloc(16384*4);
  float* WCt0   = (float*)alloc(16384*4);
  float* WCt1   = (float*)alloc(16384*4);
  float* WfT    = (float*)alloc(5120*4);
  float* bf     = (float*)alloc(64*4);
  float* H1     = (float*)alloc((size_t)NN*128*4);
  float* AGG    = (float*)alloc((size_t)NN*128*4);
  float* JKb    = (float*)alloc((size_t)NN*128*4);

  k_init_cnt<<<196, 256, 0, stream>>>(cnt);
  k_count<<<3125, 256, 0, stream>>>(ei, cnt);
  k_dis<<<196, 256, 0, stream>>>(cnt, dis);
  k_scan_blocks<<<49, 256, 0, stream>>>(cnt, offs, bsums);
  k_scan_bsums<<<1, 64, 0, stream>>>(bsums);
  k_finalize<<<196, 256, 0, stream>>>(offs, bsums, cursor);
  k_fill<<<3321, 256, 0, stream>>>(ei, dis, cursor, csr_s, csr_n);
  k_transpose<<<64, 256, 0, stream>>>(fc0_w, Wt0);
  k_combine_wc<<<64, 256, 0, stream>>>(Ww, convw, WCt0);
  k_combine_wc<<<64, 256, 0, stream>>>(Ww, convw + 16384, WCt1);
  k_combine_final<<<20, 256, 0, stream>>>(outw, fow, fob, outb, WfT, bf);

  k_gemm<1><<<391, 512, 0, stream>>>(x, Wt0, fc0_b, bng, bnb, H1, JKb);
  k_gather<<<12500, 256, 0, stream>>>(H1, csr_s, csr_n, offs, cnt, AGG);
  k_gemm<2><<<391, 512, 0, stream>>>(AGG, WCt0, Wb, bng + 128, bnb + 128, H1, JKb);
  k_gather<<<12500, 256, 0, stream>>>(H1, csr_s, csr_n, offs, cnt, AGG);
  k_gemm<2><<<391, 512, 0, stream>>>(AGG, WCt1, Wb, bng + 256, bnb + 256, H1, JKb);
  k_gemm_final<<<391, 128, 0, stream>>>(JKb, WfT, bf, out);
}

// Round 2
// 403.745 us; speedup vs baseline: 1.0348x; 1.0348x over previous
//
#include <hip/hip_runtime.h>

#define NN 50000
#define NE 800000
#define EN 850000

static constexpr float BN_SC = 0.99999500003749968f; // 1/sqrt(1+1e-5)

__device__ __forceinline__ float4 ld4(const float* p){ return *reinterpret_cast<const float4*>(p); }
__device__ __forceinline__ void st4(float* p, float4 v){ *reinterpret_cast<float4*>(p) = v; }

extern "C" __global__ void k_init_cnt(int* __restrict__ cnt){
  int i = blockIdx.x*256 + threadIdx.x;
  if (i < NN) cnt[i] = 1;                 // self-loop
}

extern "C" __global__ void k_count(const int* __restrict__ ei, int* __restrict__ cnt){
  int e = blockIdx.x*256 + threadIdx.x;
  if (e < NE) atomicAdd(&cnt[ei[NE + e]], 1);   // dst row of edge_index
}

// ---- scan of cnt -> offs (1024 elems / block); also emits dis = rsqrt(cnt) ----
extern "C" __global__ void k_scan_blocks(const int* __restrict__ cnt, int* __restrict__ offs,
                                         int* __restrict__ bsums, float* __restrict__ dis){
  __shared__ int lds[256];
  int t = threadIdx.x, b = blockIdx.x;
  int base = b*1024 + t*4;
  int v0 = (base+0 < NN) ? cnt[base+0] : 0;
  int v1 = (base+1 < NN) ? cnt[base+1] : 0;
  int v2 = (base+2 < NN) ? cnt[base+2] : 0;
  int v3 = (base+3 < NN) ? cnt[base+3] : 0;
  if (base+0 < NN) dis[base+0] = rsqrtf((float)v0);
  if (base+1 < NN) dis[base+1] = rsqrtf((float)v1);
  if (base+2 < NN) dis[base+2] = rsqrtf((float)v2);
  if (base+3 < NN) dis[base+3] = rsqrtf((float)v3);
  int s = v0+v1+v2+v3;
  lds[t] = s;
  __syncthreads();
  int acc = s;
  #pragma unroll
  for (int off = 1; off < 256; off <<= 1){
    int x = (t >= off) ? lds[t-off] : 0;
    __syncthreads();
    acc += x;
    lds[t] = acc;
    __syncthreads();
  }
  int p = acc - s;  // exclusive prefix within block
  if (base+0 < NN) offs[base+0] = p;
  if (base+1 < NN) offs[base+1] = p + v0;
  if (base+2 < NN) offs[base+2] = p + v0 + v1;
  if (base+3 < NN) offs[base+3] = p + v0 + v1 + v2;
  if (t == 255) bsums[b] = acc;
}

extern "C" __global__ void k_scan_bsums(int* __restrict__ bsums){
  __shared__ int lds[64];
  int t = threadIdx.x;
  lds[t] = (t < 49) ? bsums[t] : 0;
  __syncthreads();
  if (t == 0){
    int run = 0;
    for (int i = 0; i < 49; ++i){ int x = lds[i]; lds[i] = run; run += x; }
  }
  __syncthreads();
  if (t < 49) bsums[t] = lds[t];
}

extern "C" __global__ void k_finalize(int* __restrict__ offs, const int* __restrict__ bsums,
                                      int* __restrict__ cursor){
  int i = blockIdx.x*256 + threadIdx.x;
  if (i < NN){ int v = offs[i] + bsums[i >> 10]; offs[i] = v; cursor[i] = v; }
}

// Place edges into CSR-by-dst. Only the src id is stored (norm recomputed at gather).
extern "C" __global__ void k_fill(const int* __restrict__ ei, int* __restrict__ cursor,
                                  int* __restrict__ csr_s){
  int e = blockIdx.x*256 + threadIdx.x;
  if (e >= EN) return;
  int s, d;
  if (e < NE){ s = ei[e]; d = ei[NE + e]; } else { s = e - NE; d = s; }
  int pos = atomicAdd(&cursor[d], 1);
  csr_s[pos] = s;
}

// Fused weight prep, dispatched by blockIdx range:
//  [0,64)    Wt0[k][f]  = fc0_w[f][k]
//  [64,128)  WCt0[k][f] = (Ww @ conv_w[0])[f][k]
//  [128,192) WCt1[k][f] = (Ww @ conv_w[1])[f][k]
//  [192,212) WfT[k][c]  = (out_w @ fc_out_w)[c][k]; bf[c] = out_b[c] + out_w[c].fc_out_b
extern "C" __global__ void k_wprep(const float* __restrict__ fc0_w,
                                   const float* __restrict__ Ww, const float* __restrict__ cw,
                                   const float* __restrict__ ow, const float* __restrict__ fw,
                                   const float* __restrict__ fb, const float* __restrict__ ob,
                                   float* __restrict__ Wt0, float* __restrict__ WCt0,
                                   float* __restrict__ WCt1, float* __restrict__ WfT,
                                   float* __restrict__ bf){
  int b = blockIdx.x;
  if (b < 64){
    int idx = b*256 + threadIdx.x;
    int f = idx >> 7, k = idx & 127;
    Wt0[k*128 + f] = fc0_w[f*128 + k];
  } else if (b < 192){
    int idx = (b & 63)*256 + threadIdx.x;
    int f = idx >> 7, k = idx & 127;
    const float* c = (b < 128) ? cw : (cw + 16384);
    float acc = 0.f;
    #pragma unroll 4
    for (int j = 0; j < 128; ++j) acc = fmaf(Ww[f*128 + j], c[j*128 + k], acc);
    float* o = (b < 128) ? WCt0 : WCt1;
    o[k*128 + f] = acc;
  } else {
    int idx = (b - 192)*256 + threadIdx.x;
    if (idx < 5120){
      int c = idx >> 7, k = idx & 127;
      float acc = 0.f;
      for (int j = 0; j < 128; ++j) acc = fmaf(ow[c*128 + j], fw[j*128 + k], acc);
      WfT[k*40 + c] = acc;
    }
    if (idx < 40){
      float acc = ob[idx];
      for (int j = 0; j < 128; ++j) acc = fmaf(ow[idx*128 + j], fb[j], acc);
      bf[idx] = acc;
    }
  }
}

// Agg[n] = sum_{e in CSR[n]} dis[s_e]*dis[n] * Hf[s_e]  -- one wave per node, 2 edges/iter
extern "C" __global__ __launch_bounds__(256)
void k_gather(const float* __restrict__ Hf, const int* __restrict__ csr_s,
              const float* __restrict__ dis, const int* __restrict__ offs,
              const int* __restrict__ cnt, float* __restrict__ Agg){
  int lane = threadIdx.x & 63;
  int node = blockIdx.x*4 + (threadIdx.x >> 6);
  int half = lane >> 5;
  int q4 = (lane & 31)*4;
  int start = offs[node];
  int n = cnt[node];
  float dn = dis[node];
  float ax = 0.f, ay = 0.f, az = 0.f, aw = 0.f;
  for (int k = half; k < n; k += 2){
    int e = start + k;
    int s = csr_s[e];
    float nv = dis[s];                    // broadcast L2 hit within half-wave
    float4 v = ld4(Hf + s*128 + q4);
    ax = fmaf(v.x, nv, ax); ay = fmaf(v.y, nv, ay);
    az = fmaf(v.z, nv, az); aw = fmaf(v.w, nv, aw);
  }
  ax += __shfl_xor(ax, 32); ay += __shfl_xor(ay, 32);
  az += __shfl_xor(az, 32); aw += __shfl_xor(aw, 32);
  if (half == 0){
    float4 o; o.x = ax*dn; o.y = ay*dn; o.z = az*dn; o.w = aw*dn;
    st4(Agg + node*128 + q4, o);
  }
}

// C = relu(bn((X @ W^T) + bias));  MODE 1: Jk = C;  MODE 2: Jk = max(Jk, C).
template<int MODE>
__global__ __launch_bounds__(512, 4)
void k_gemm(const float* __restrict__ X, const float* __restrict__ Wt,
            const float* __restrict__ bias, const float* __restrict__ gamma,
            const float* __restrict__ beta, float* __restrict__ Cout,
            float* __restrict__ Jk){
  __shared__ float Bs[128][128];
  const int t = threadIdx.x;
  {
    const float4* src = reinterpret_cast<const float4*>(Wt);
    float4* dst = reinterpret_cast<float4*>(&Bs[0][0]);
    #pragma unroll
    for (int it = 0; it < 8; ++it) dst[it*512 + t] = src[it*512 + t];
  }
  __syncthreads();
  const int c4 = (t & 31)*4;
  const int tr = t >> 5;
  const int m0 = blockIdx.x*128 + tr*4;
  int off[8];
  #pragma unroll
  for (int r = 0; r < 8; ++r){
    int m = m0 + (r & 3) + (r >> 2)*64;
    off[r] = (m < NN ? m : 0)*128;   // clamp OOB rows; store is guarded below
  }
  float acc[8][4] = {};
  for (int kk = 0; kk < 128; kk += 4){
    float b[4][4];
    #pragma unroll
    for (int j = 0; j < 4; ++j){
      float4 v = ld4(&Bs[kk+j][c4]);
      b[j][0] = v.x; b[j][1] = v.y; b[j][2] = v.z; b[j][3] = v.w;
    }
    #pragma unroll
    for (int r = 0; r < 8; ++r){
      float4 v = ld4(X + off[r] + kk);
      #pragma unroll
      for (int q = 0; q < 4; ++q){
        acc[r][q] = fmaf(v.x, b[0][q], acc[r][q]);
        acc[r][q] = fmaf(v.y, b[1][q], acc[r][q]);
        acc[r][q] = fmaf(v.z, b[2][q], acc[r][q]);
        acc[r][q] = fmaf(v.w, b[3][q], acc[r][q]);
      }
    }
  }
  float4 bi = ld4(bias + c4);
  float4 g  = ld4(gamma + c4);
  float4 be = ld4(beta + c4);
  float sc0 = g.x*BN_SC, sc1 = g.y*BN_SC, sc2 = g.z*BN_SC, sc3 = g.w*BN_SC;
  #pragma unroll
  for (int r = 0; r < 8; ++r){
    int m = m0 + (r & 3) + (r >> 2)*64;
    if (m < NN){
      float4 o;
      o.x = fmaxf(fmaf(acc[r][0] + bi.x, sc0, be.x), 0.f);
      o.y = fmaxf(fmaf(acc[r][1] + bi.y, sc1, be.y), 0.f);
      o.z = fmaxf(fmaf(acc[r][2] + bi.z, sc2, be.z), 0.f);
      o.w = fmaxf(fmaf(acc[r][3] + bi.w, sc3, be.w), 0.f);
      if (MODE == 1){
        st4(Cout + m*128 + c4, o);
        st4(Jk + m*128 + c4, o);
      } else {
        float4 jo = ld4(Jk + m*128 + c4);
        float4 nj;
        nj.x = fmaxf(jo.x, o.x); nj.y = fmaxf(jo.y, o.y);
        nj.z = fmaxf(jo.z, o.z); nj.w = fmaxf(jo.w, o.w);
        st4(Cout + m*128 + c4, o);
        st4(Jk + m*128 + c4, nj);
      }
    }
  }
}

// Out[m][c] = X[m] . WfT[:][c] + bf[c]   (C=40), BM=128, 128 threads, 8x5 acc
__global__ __launch_bounds__(128)
void k_gemm_final(const float* __restrict__ X, const float* __restrict__ WfT,
                  const float* __restrict__ bf, float* __restrict__ Out){
  __shared__ float Bs[5120];
  const int t = threadIdx.x;
  #pragma unroll
  for (int it = 0; it < 40; ++it) Bs[it*128 + t] = WfT[it*128 + t];
  __syncthreads();
  const int cg = (t & 7)*5;
  const int tr = t >> 3;
  const int m0 = blockIdx.x*128 + tr*4;
  int off[8];
  #pragma unroll
  for (int r = 0; r < 8; ++r){
    int m = m0 + (r & 3) + (r >> 2)*64;
    off[r] = (m < NN ? m : 0)*128;
  }
  float acc[8][5] = {};
  for (int kk = 0; kk < 128; kk += 4){
    float b[4][5];
    #pragma unroll
    for (int j = 0; j < 4; ++j)
      #pragma unroll
      for (int q = 0; q < 5; ++q)
        b[j][q] = Bs[(kk+j)*40 + cg + q];
    #pragma unroll
    for (int r = 0; r < 8; ++r){
      float4 v = ld4(X + off[r] + kk);
      #pragma unroll
      for (int q = 0; q < 5; ++q){
        acc[r][q] = fmaf(v.x, b[0][q], acc[r][q]);
        acc[r][q] = fmaf(v.y, b[1][q], acc[r][q]);
        acc[r][q] = fmaf(v.z, b[2][q], acc[r][q]);
        acc[r][q] = fmaf(v.w, b[3][q], acc[r][q]);
      }
    }
  }
  float bb[5];
  #pragma unroll
  for (int q = 0; q < 5; ++q) bb[q] = bf[cg + q];
  #pragma unroll
  for (int r = 0; r < 8; ++r){
    int m = m0 + (r & 3) + (r >> 2)*64;
    if (m < NN){
      #pragma unroll
      for (int q = 0; q < 5; ++q) Out[m*40 + cg + q] = acc[r][q] + bb[q];
    }
  }
}

extern "C" void kernel_launch(void* const* d_in, const int* in_sizes, int n_in,
                              void* d_out, int out_size, void* d_ws, size_t ws_size,
                              hipStream_t stream){
  const float* x     = (const float*)d_in[0];
  const int*   ei    = (const int*)d_in[1];
  const float* fc0_w = (const float*)d_in[2];
  const float* fc0_b = (const float*)d_in[3];
  const float* convw = (const float*)d_in[4];
  const float* Ww    = (const float*)d_in[5];
  const float* Wb    = (const float*)d_in[6];
  const float* bng   = (const float*)d_in[7];
  const float* bnb   = (const float*)d_in[8];
  const float* fow   = (const float*)d_in[9];
  const float* fob   = (const float*)d_in[10];
  const float* outw  = (const float*)d_in[11];
  const float* outb  = (const float*)d_in[12];
  float* out = (float*)d_out;

  char* p = (char*)d_ws;
  auto alloc = [&](size_t n){ char* r = p; p += (n + 255) & ~(size_t)255; return r; };
  int*   cnt    = (int*)  alloc((size_t)NN*4);
  int*   offs   = (int*)  alloc((size_t)NN*4);
  int*   cursor = (int*)  alloc((size_t)NN*4);
  float* dis    = (float*)alloc((size_t)NN*4);
  int*   bsums  = (int*)  alloc(64*4);
  int*   csr_s  = (int*)  alloc((size_t)EN*4);
  float* Wt0    = (float*)alloc(16384*4);
  float* WCt0   = (float*)alloc(16384*4);
  float* WCt1   = (float*)alloc(16384*4);
  float* WfT    = (float*)alloc(5120*4);
  float* bf     = (float*)alloc(64*4);
  float* H1     = (float*)alloc((size_t)NN*128*4);
  float* AGG    = (float*)alloc((size_t)NN*128*4);
  float* JKb    = (float*)alloc((size_t)NN*128*4);

  k_init_cnt<<<196, 256, 0, stream>>>(cnt);
  k_count<<<3125, 256, 0, stream>>>(ei, cnt);
  k_scan_blocks<<<49, 256, 0, stream>>>(cnt, offs, bsums, dis);
  k_scan_bsums<<<1, 64, 0, stream>>>(bsums);
  k_finalize<<<196, 256, 0, stream>>>(offs, bsums, cursor);
  k_fill<<<3321, 256, 0, stream>>>(ei, cursor, csr_s);
  k_wprep<<<212, 256, 0, stream>>>(fc0_w, Ww, convw, outw, fow, fob, outb,
                                   Wt0, WCt0, WCt1, WfT, bf);

  k_gemm<1><<<391, 512, 0, stream>>>(x, Wt0, fc0_b, bng, bnb, H1, JKb);
  k_gather<<<12500, 256, 0, stream>>>(H1, csr_s, dis, offs, cnt, AGG);
  k_gemm<2><<<391, 512, 0, stream>>>(AGG, WCt0, Wb, bng + 128, bnb + 128, H1, JKb);
  k_gather<<<12500, 256, 0, stream>>>(H1, csr_s, dis, offs, cnt, AGG);
  k_gemm<2><<<391, 512, 0, stream>>>(AGG, WCt1, Wb, bng + 256, bnb + 256, H1, JKb);
  k_gemm_final<<<391, 128, 0, stream>>>(JKb, WfT, bf, out);
}

// Round 3
// 385.381 us; speedup vs baseline: 1.0841x; 1.0477x over previous
//
#include <hip/hip_runtime.h>

#define NN 50000
#define NE 800000
#define EN 850000

static constexpr float BN_SC = 0.99999500003749968f; // 1/sqrt(1+1e-5)

__device__ __forceinline__ float4 ld4(const float* p){ return *reinterpret_cast<const float4*>(p); }
__device__ __forceinline__ void st4(float* p, float4 v){ *reinterpret_cast<float4*>(p) = v; }

__device__ __forceinline__ float bf2f(unsigned short u){
  union { unsigned int i; float f; } v; v.i = ((unsigned int)u) << 16; return v.f;
}
__device__ __forceinline__ unsigned short f2bf(float f){
  union { float f; unsigned int i; } v; v.f = f;
  unsigned int r = v.i + 0x7fffu + ((v.i >> 16) & 1u);   // RNE
  return (unsigned short)(r >> 16);
}

extern "C" __global__ void k_init_cnt(int* __restrict__ cnt){
  int i = blockIdx.x*256 + threadIdx.x;
  if (i < NN) cnt[i] = 1;                 // self-loop
}

extern "C" __global__ void k_count(const int* __restrict__ ei, int* __restrict__ cnt){
  int e = blockIdx.x*256 + threadIdx.x;
  if (e < NE) atomicAdd(&cnt[ei[NE + e]], 1);   // dst row of edge_index
}

// ---- scan of cnt -> offs (1024 elems / block); also emits dis = rsqrt(cnt) ----
extern "C" __global__ void k_scan_blocks(const int* __restrict__ cnt, int* __restrict__ offs,
                                         int* __restrict__ bsums, float* __restrict__ dis){
  __shared__ int lds[256];
  int t = threadIdx.x, b = blockIdx.x;
  int base = b*1024 + t*4;
  int v0 = (base+0 < NN) ? cnt[base+0] : 0;
  int v1 = (base+1 < NN) ? cnt[base+1] : 0;
  int v2 = (base+2 < NN) ? cnt[base+2] : 0;
  int v3 = (base+3 < NN) ? cnt[base+3] : 0;
  if (base+0 < NN) dis[base+0] = rsqrtf((float)v0);
  if (base+1 < NN) dis[base+1] = rsqrtf((float)v1);
  if (base+2 < NN) dis[base+2] = rsqrtf((float)v2);
  if (base+3 < NN) dis[base+3] = rsqrtf((float)v3);
  int s = v0+v1+v2+v3;
  lds[t] = s;
  __syncthreads();
  int acc = s;
  #pragma unroll
  for (int off = 1; off < 256; off <<= 1){
    int x = (t >= off) ? lds[t-off] : 0;
    __syncthreads();
    acc += x;
    lds[t] = acc;
    __syncthreads();
  }
  int p = acc - s;  // exclusive prefix within block
  if (base+0 < NN) offs[base+0] = p;
  if (base+1 < NN) offs[base+1] = p + v0;
  if (base+2 < NN) offs[base+2] = p + v0 + v1;
  if (base+3 < NN) offs[base+3] = p + v0 + v1 + v2;
  if (t == 255) bsums[b] = acc;
}

extern "C" __global__ void k_scan_bsums(int* __restrict__ bsums){
  __shared__ int lds[64];
  int t = threadIdx.x;
  lds[t] = (t < 49) ? bsums[t] : 0;
  __syncthreads();
  if (t == 0){
    int run = 0;
    for (int i = 0; i < 49; ++i){ int x = lds[i]; lds[i] = run; run += x; }
  }
  __syncthreads();
  if (t < 49) bsums[t] = lds[t];
}

extern "C" __global__ void k_finalize(int* __restrict__ offs, const int* __restrict__ bsums,
                                      int* __restrict__ cursor){
  int i = blockIdx.x*256 + threadIdx.x;
  if (i < NN){ int v = offs[i] + bsums[i >> 10]; offs[i] = v; cursor[i] = v; }
}

// Place edges into CSR-by-dst. Only the src id is stored (norm recomputed at gather).
extern "C" __global__ void k_fill(const int* __restrict__ ei, int* __restrict__ cursor,
                                  int* __restrict__ csr_s){
  int e = blockIdx.x*256 + threadIdx.x;
  if (e >= EN) return;
  int s, d;
  if (e < NE){ s = ei[e]; d = ei[NE + e]; } else { s = e - NE; d = s; }
  int pos = atomicAdd(&cursor[d], 1);
  csr_s[pos] = s;
}

// Fused weight prep, dispatched by blockIdx range (see round-2 comment).
extern "C" __global__ void k_wprep(const float* __restrict__ fc0_w,
                                   const float* __restrict__ Ww, const float* __restrict__ cw,
                                   const float* __restrict__ ow, const float* __restrict__ fw,
                                   const float* __restrict__ fb, const float* __restrict__ ob,
                                   float* __restrict__ Wt0, float* __restrict__ WCt0,
                                   float* __restrict__ WCt1, float* __restrict__ WfT,
                                   float* __restrict__ bf){
  int b = blockIdx.x;
  if (b < 64){
    int idx = b*256 + threadIdx.x;
    int f = idx >> 7, k = idx & 127;
    Wt0[k*128 + f] = fc0_w[f*128 + k];
  } else if (b < 192){
    int idx = (b & 63)*256 + threadIdx.x;
    int f = idx >> 7, k = idx & 127;
    const float* c = (b < 128) ? cw : (cw + 16384);
    float acc = 0.f;
    #pragma unroll 4
    for (int j = 0; j < 128; ++j) acc = fmaf(Ww[f*128 + j], c[j*128 + k], acc);
    float* o = (b < 128) ? WCt0 : WCt1;
    o[k*128 + f] = acc;
  } else {
    int idx = (b - 192)*256 + threadIdx.x;
    if (idx < 5120){
      int c = idx >> 7, k = idx & 127;
      float acc = 0.f;
      for (int j = 0; j < 128; ++j) acc = fmaf(ow[c*128 + j], fw[j*128 + k], acc);
      WfT[k*40 + c] = acc;
    }
    if (idx < 40){
      float acc = ob[idx];
      for (int j = 0; j < 128; ++j) acc = fmaf(ow[idx*128 + j], fb[j], acc);
      bf[idx] = acc;
    }
  }
}

// Agg[n] = dis[n] * sum_e dis[s_e] * Hf[s_e]  -- bf16 rows, one wave/node, 2 edges/iter
extern "C" __global__ __launch_bounds__(256)
void k_gather(const unsigned short* __restrict__ Hf, const int* __restrict__ csr_s,
              const float* __restrict__ dis, const int* __restrict__ offs,
              const int* __restrict__ cnt, unsigned short* __restrict__ Agg){
  int lane = threadIdx.x & 63;
  int node = blockIdx.x*4 + (threadIdx.x >> 6);
  int half = lane >> 5;
  int q4 = (lane & 31)*4;
  int start = offs[node];
  int n = cnt[node];
  float dn = dis[node];
  float ax = 0.f, ay = 0.f, az = 0.f, aw = 0.f;
  for (int k = half; k < n; k += 2){
    int e = start + k;
    int s = csr_s[e];
    float nv = dis[s];                    // broadcast load within half-wave
    ushort4 u = *reinterpret_cast<const ushort4*>(Hf + s*128 + q4);
    ax = fmaf(bf2f(u.x), nv, ax); ay = fmaf(bf2f(u.y), nv, ay);
    az = fmaf(bf2f(u.z), nv, az); aw = fmaf(bf2f(u.w), nv, aw);
  }
  ax += __shfl_xor(ax, 32); ay += __shfl_xor(ay, 32);
  az += __shfl_xor(az, 32); aw += __shfl_xor(aw, 32);
  if (half == 0){
    ushort4 o;
    o.x = f2bf(ax*dn); o.y = f2bf(ay*dn); o.z = f2bf(az*dn); o.w = f2bf(aw*dn);
    *reinterpret_cast<ushort4*>(Agg + node*128 + q4) = o;
  }
}

// C = relu(bn((X @ W^T) + bias)) -> bf16;  MODE 1: X fp32, Jk = C;  MODE 2: X bf16, Jk = max(Jk, C).
// Jk stays fp32 (computed from pre-rounding values).
template<int MODE>
__global__ __launch_bounds__(512, 4)
void k_gemm(const float* __restrict__ Xf, const unsigned short* __restrict__ Xb,
            const float* __restrict__ Wt, const float* __restrict__ bias,
            const float* __restrict__ gamma, const float* __restrict__ beta,
            unsigned short* __restrict__ Cout, float* __restrict__ Jk){
  __shared__ float Bs[128][128];
  const int t = threadIdx.x;
  {
    const float4* src = reinterpret_cast<const float4*>(Wt);
    float4* dst = reinterpret_cast<float4*>(&Bs[0][0]);
    #pragma unroll
    for (int it = 0; it < 8; ++it) dst[it*512 + t] = src[it*512 + t];
  }
  __syncthreads();
  const int c4 = (t & 31)*4;
  const int tr = t >> 5;
  const int m0 = blockIdx.x*128 + tr*4;
  int off[8];
  #pragma unroll
  for (int r = 0; r < 8; ++r){
    int m = m0 + (r & 3) + (r >> 2)*64;
    off[r] = (m < NN ? m : 0)*128;   // clamp OOB rows; store is guarded below
  }
  float acc[8][4] = {};
  for (int kk = 0; kk < 128; kk += 4){
    float b[4][4];
    #pragma unroll
    for (int j = 0; j < 4; ++j){
      float4 v = ld4(&Bs[kk+j][c4]);
      b[j][0] = v.x; b[j][1] = v.y; b[j][2] = v.z; b[j][3] = v.w;
    }
    #pragma unroll
    for (int r = 0; r < 8; ++r){
      float4 v;
      if constexpr (MODE == 1){
        v = ld4(Xf + off[r] + kk);
      } else {
        ushort4 u = *reinterpret_cast<const ushort4*>(Xb + off[r] + kk);
        v.x = bf2f(u.x); v.y = bf2f(u.y); v.z = bf2f(u.z); v.w = bf2f(u.w);
      }
      #pragma unroll
      for (int q = 0; q < 4; ++q){
        acc[r][q] = fmaf(v.x, b[0][q], acc[r][q]);
        acc[r][q] = fmaf(v.y, b[1][q], acc[r][q]);
        acc[r][q] = fmaf(v.z, b[2][q], acc[r][q]);
        acc[r][q] = fmaf(v.w, b[3][q], acc[r][q]);
      }
    }
  }
  float4 bi = ld4(bias + c4);
  float4 g  = ld4(gamma + c4);
  float4 be = ld4(beta + c4);
  float sc0 = g.x*BN_SC, sc1 = g.y*BN_SC, sc2 = g.z*BN_SC, sc3 = g.w*BN_SC;
  #pragma unroll
  for (int r = 0; r < 8; ++r){
    int m = m0 + (r & 3) + (r >> 2)*64;
    if (m < NN){
      float4 o;
      o.x = fmaxf(fmaf(acc[r][0] + bi.x, sc0, be.x), 0.f);
      o.y = fmaxf(fmaf(acc[r][1] + bi.y, sc1, be.y), 0.f);
      o.z = fmaxf(fmaf(acc[r][2] + bi.z, sc2, be.z), 0.f);
      o.w = fmaxf(fmaf(acc[r][3] + bi.w, sc3, be.w), 0.f);
      ushort4 ob;
      ob.x = f2bf(o.x); ob.y = f2bf(o.y); ob.z = f2bf(o.z); ob.w = f2bf(o.w);
      *reinterpret_cast<ushort4*>(Cout + m*128 + c4) = ob;
      if (MODE == 1){
        st4(Jk + m*128 + c4, o);
      } else {
        float4 jo = ld4(Jk + m*128 + c4);
        float4 nj;
        nj.x = fmaxf(jo.x, o.x); nj.y = fmaxf(jo.y, o.y);
        nj.z = fmaxf(jo.z, o.z); nj.w = fmaxf(jo.w, o.w);
        st4(Jk + m*128 + c4, nj);
      }
    }
  }
}

// Out[m][c] = X[m] . WfT[:][c] + bf[c]   (C=40), BM=128, 128 threads, 8x5 acc
__global__ __launch_bounds__(128)
void k_gemm_final(const float* __restrict__ X, const float* __restrict__ WfT,
                  const float* __restrict__ bf, float* __restrict__ Out){
  __shared__ float Bs[5120];
  const int t = threadIdx.x;
  #pragma unroll
  for (int it = 0; it < 40; ++it) Bs[it*128 + t] = WfT[it*128 + t];
  __syncthreads();
  const int cg = (t & 7)*5;
  const int tr = t >> 3;
  const int m0 = blockIdx.x*128 + tr*4;
  int off[8];
  #pragma unroll
  for (int r = 0; r < 8; ++r){
    int m = m0 + (r & 3) + (r >> 2)*64;
    off[r] = (m < NN ? m : 0)*128;
  }
  float acc[8][5] = {};
  for (int kk = 0; kk < 128; kk += 4){
    float b[4][5];
    #pragma unroll
    for (int j = 0; j < 4; ++j)
      #pragma unroll
      for (int q = 0; q < 5; ++q)
        b[j][q] = Bs[(kk+j)*40 + cg + q];
    #pragma unroll
    for (int r = 0; r < 8; ++r){
      float4 v = ld4(X + off[r] + kk);
      #pragma unroll
      for (int q = 0; q < 5; ++q){
        acc[r][q] = fmaf(v.x, b[0][q], acc[r][q]);
        acc[r][q] = fmaf(v.y, b[1][q], acc[r][q]);
        acc[r][q] = fmaf(v.z, b[2][q], acc[r][q]);
        acc[r][q] = fmaf(v.w, b[3][q], acc[r][q]);
      }
    }
  }
  float bb[5];
  #pragma unroll
  for (int q = 0; q < 5; ++q) bb[q] = bf[cg + q];
  #pragma unroll
  for (int r = 0; r < 8; ++r){
    int m = m0 + (r & 3) + (r >> 2)*64;
    if (m < NN){
      #pragma unroll
      for (int q = 0; q < 5; ++q) Out[m*40 + cg + q] = acc[r][q] + bb[q];
    }
  }
}

extern "C" void kernel_launch(void* const* d_in, const int* in_sizes, int n_in,
                              void* d_out, int out_size, void* d_ws, size_t ws_size,
                              hipStream_t stream){
  const float* x     = (const float*)d_in[0];
  const int*   ei    = (const int*)d_in[1];
  const float* fc0_w = (const float*)d_in[2];
  const float* fc0_b = (const float*)d_in[3];
  const float* convw = (const float*)d_in[4];
  const float* Ww    = (const float*)d_in[5];
  const float* Wb    = (const float*)d_in[6];
  const float* bng   = (const float*)d_in[7];
  const float* bnb   = (const float*)d_in[8];
  const float* fow   = (const float*)d_in[9];
  const float* fob   = (const float*)d_in[10];
  const float* outw  = (const float*)d_in[11];
  const float* outb  = (const float*)d_in[12];
  float* out = (float*)d_out;

  char* p = (char*)d_ws;
  auto alloc = [&](size_t n){ char* r = p; p += (n + 255) & ~(size_t)255; return r; };
  int*   cnt    = (int*)  alloc((size_t)NN*4);
  int*   offs   = (int*)  alloc((size_t)NN*4);
  int*   cursor = (int*)  alloc((size_t)NN*4);
  float* dis    = (float*)alloc((size_t)NN*4);
  int*   bsums  = (int*)  alloc(64*4);
  int*   csr_s  = (int*)  alloc((size_t)EN*4);
  float* Wt0    = (float*)alloc(16384*4);
  float* WCt0   = (float*)alloc(16384*4);
  float* WCt1   = (float*)alloc(16384*4);
  float* WfT    = (float*)alloc(5120*4);
  float* bf     = (float*)alloc(64*4);
  unsigned short* H1  = (unsigned short*)alloc((size_t)NN*128*2);
  unsigned short* AGG = (unsigned short*)alloc((size_t)NN*128*2);
  float* JKb    = (float*)alloc((size_t)NN*128*4);

  k_init_cnt<<<196, 256, 0, stream>>>(cnt);
  k_count<<<3125, 256, 0, stream>>>(ei, cnt);
  k_scan_blocks<<<49, 256, 0, stream>>>(cnt, offs, bsums, dis);
  k_scan_bsums<<<1, 64, 0, stream>>>(bsums);
  k_finalize<<<196, 256, 0, stream>>>(offs, bsums, cursor);
  k_fill<<<3321, 256, 0, stream>>>(ei, cursor, csr_s);
  k_wprep<<<212, 256, 0, stream>>>(fc0_w, Ww, convw, outw, fow, fob, outb,
                                   Wt0, WCt0, WCt1, WfT, bf);

  k_gemm<1><<<391, 512, 0, stream>>>(x, nullptr, Wt0, fc0_b, bng, bnb, H1, JKb);
  k_gather<<<12500, 256, 0, stream>>>(H1, csr_s, dis, offs, cnt, AGG);
  k_gemm<2><<<391, 512, 0, stream>>>(nullptr, AGG, WCt0, Wb, bng + 128, bnb + 128, H1, JKb);
  k_gather<<<12500, 256, 0, stream>>>(H1, csr_s, dis, offs, cnt, AGG);
  k_gemm<2><<<391, 512, 0, stream>>>(nullptr, AGG, WCt1, Wb, bng + 256, bnb + 256, H1, JKb);
  k_gemm_final<<<391, 128, 0, stream>>>(JKb, WfT, bf, out);
}

// Round 4
// 324.442 us; speedup vs baseline: 1.2878x; 1.1878x over previous
//
#include <hip/hip_runtime.h>

#define NN 50000
#define NE 800000
#define EN 850000
#define NB 196       // dst buckets of 256 nodes
#define BINBLK 391   // ceil(NE/2048)

static constexpr float BN_SC = 0.99999500003749968f; // 1/sqrt(1+1e-5)

__device__ __forceinline__ float4 ld4(const float* p){ return *reinterpret_cast<const float4*>(p); }
__device__ __forceinline__ void st4(float* p, float4 v){ *reinterpret_cast<float4*>(p) = v; }

__device__ __forceinline__ float bf2f(unsigned short u){
  union { unsigned int i; float f; } v; v.i = ((unsigned int)u) << 16; return v.f;
}
__device__ __forceinline__ unsigned short f2bf(float f){
  union { float f; unsigned int i; } v; v.f = f;
  unsigned int r = v.i + 0x7fffu + ((v.i >> 16) & 1u);   // RNE
  return (unsigned short)(r >> 16);
}

// ---- Level-0: per-bucket edge histogram (LDS-privatized) ----
extern "C" __global__ __launch_bounds__(256)
void k_bhist(const int* __restrict__ ei, int* __restrict__ gbucket){
  __shared__ int h[NB];
  int t = threadIdx.x;
  if (t < NB) h[t] = 0;
  __syncthreads();
  int e0 = blockIdx.x*2048;
  for (int i = t; i < 2048; i += 256){
    int e = e0 + i;
    if (e < NE) atomicAdd(&h[ei[NE+e] >> 8], 1);
  }
  __syncthreads();
  if (t < NB && h[t] > 0) atomicAdd(&gbucket[t], h[t]);
}

// ---- bucket base offsets (edge-only and with analytic self-loops) ----
extern "C" __global__ void k_bscan(const int* __restrict__ gbucket, int* __restrict__ ebase,
                                   int* __restrict__ tbase, int* __restrict__ gcur){
  if (threadIdx.x == 0){
    int runE = 0, runT = 0;
    for (int b = 0; b < NB; ++b){
      int ge = gbucket[b];
      int sc = (b < NB-1) ? 256 : (NN - (NB-1)*256);
      ebase[b] = runE; gcur[b] = runE; tbase[b] = runT;
      runE += ge; runT += ge + sc;
    }
    ebase[NB] = runE; tbase[NB] = runT;
  }
}

// ---- Level-1: bin edges by bucket; LDS-staged, run-coalesced flush ----
extern "C" __global__ __launch_bounds__(256)
void k_bin(const int* __restrict__ ei, int* __restrict__ gcur, unsigned int* __restrict__ bbuf){
  __shared__ int h[NB], lbase[NB], gbase[NB];
  __shared__ int tot;
  __shared__ unsigned int stage[2048];
  __shared__ unsigned char bid[2048];
  int t = threadIdx.x;
  if (t < NB) h[t] = 0;
  __syncthreads();
  int e0 = blockIdx.x*2048;
  for (int i = t; i < 2048; i += 256){
    int e = e0 + i;
    if (e < NE) atomicAdd(&h[ei[NE+e] >> 8], 1);
  }
  __syncthreads();
  if (t == 0){
    int run = 0;
    for (int b = 0; b < NB; ++b){ lbase[b] = run; run += h[b]; }
    tot = run;
  }
  __syncthreads();
  if (t < NB && h[t] > 0) gbase[t] = atomicAdd(&gcur[t], h[t]);  // one atomic per (block,bucket)
  __syncthreads();
  if (t < NB) h[t] = lbase[t];      // reuse as LDS placement cursor
  __syncthreads();
  for (int i = t; i < 2048; i += 256){
    int e = e0 + i;
    if (e < NE){
      int s = ei[e], d = ei[NE+e];
      int b = d >> 8;
      int p = atomicAdd(&h[b], 1);
      stage[p] = ((unsigned int)d << 16) | (unsigned int)s;   // node ids < 2^16
      bid[p] = (unsigned char)b;
    }
  }
  __syncthreads();
  int m = tot;
  for (int j = t; j < m; j += 256){
    int b = bid[j];
    bbuf[gbase[b] + (j - lbase[b])] = stage[j];               // contiguous per-bucket runs
  }
}

// ---- Level-2: per-bucket counting sort -> final CSR (u16 src), offs, dis ----
extern "C" __global__ __launch_bounds__(256)
void k_csr(const unsigned int* __restrict__ bbuf, const int* __restrict__ ebase,
           const int* __restrict__ tbase, unsigned short* __restrict__ csr,
           int* __restrict__ offs, float* __restrict__ dis){
  __shared__ int h[256], loff[256], lcur[256];
  __shared__ unsigned short stage[8192];
  int t = threadIdx.x;
  int b = blockIdx.x;
  int nb0 = b << 8;
  int BNv = min(256, NN - nb0);
  int ebeg = ebase[b];
  int m = ebase[b+1] - ebeg;
  int base = tbase[b];
  h[t] = (t < BNv) ? 1 : 0;    // self-loop
  __syncthreads();
  for (int i = t; i < m; i += 256)
    atomicAdd(&h[(bbuf[ebeg + i] >> 16) & 255], 1);
  __syncthreads();
  if (t == 0){
    int run = 0;
    for (int n = 0; n < BNv; ++n){ loff[n] = run; run += h[n]; }
  }
  __syncthreads();
  if (t < BNv){
    offs[nb0 + t] = base + loff[t];
    dis[nb0 + t] = rsqrtf((float)h[t]);
    lcur[t] = loff[t] + 1;
    stage[loff[t]] = (unsigned short)(nb0 + t);   // self-loop edge first
  }
  if (b == NB-1 && t == 0) offs[NN] = EN;
  __syncthreads();
  for (int i = t; i < m; i += 256){
    unsigned int e = bbuf[ebeg + i];
    int p = atomicAdd(&lcur[(e >> 16) & 255], 1);
    stage[p] = (unsigned short)(e & 0xffffu);
  }
  __syncthreads();
  int M = m + BNv;
  for (int j = t; j < M; j += 256) csr[base + j] = stage[j];  // fully coalesced
}

// Fused weight prep, dispatched by blockIdx range.
extern "C" __global__ void k_wprep(const float* __restrict__ fc0_w,
                                   const float* __restrict__ Ww, const float* __restrict__ cw,
                                   const float* __restrict__ ow, const float* __restrict__ fw,
                                   const float* __restrict__ fb, const float* __restrict__ ob,
                                   float* __restrict__ Wt0, float* __restrict__ WCt0,
                                   float* __restrict__ WCt1, float* __restrict__ WfT,
                                   float* __restrict__ bf){
  int b = blockIdx.x;
  if (b < 64){
    int idx = b*256 + threadIdx.x;
    int f = idx >> 7, k = idx & 127;
    Wt0[k*128 + f] = fc0_w[f*128 + k];
  } else if (b < 192){
    int idx = (b & 63)*256 + threadIdx.x;
    int f = idx >> 7, k = idx & 127;
    const float* c = (b < 128) ? cw : (cw + 16384);
    float acc = 0.f;
    #pragma unroll 4
    for (int j = 0; j < 128; ++j) acc = fmaf(Ww[f*128 + j], c[j*128 + k], acc);
    float* o = (b < 128) ? WCt0 : WCt1;
    o[k*128 + f] = acc;
  } else {
    int idx = (b - 192)*256 + threadIdx.x;
    if (idx < 5120){
      int c = idx >> 7, k = idx & 127;
      float acc = 0.f;
      for (int j = 0; j < 128; ++j) acc = fmaf(ow[c*128 + j], fw[j*128 + k], acc);
      WfT[k*40 + c] = acc;
    }
    if (idx < 40){
      float acc = ob[idx];
      for (int j = 0; j < 128; ++j) acc = fmaf(ow[idx*128 + j], fb[j], acc);
      bf[idx] = acc;
    }
  }
}

// Agg[n] = dis[n] * sum_e dis[s_e] * Hf[s_e]  -- bf16 rows, one wave/node, 2 edges/iter
extern "C" __global__ __launch_bounds__(256)
void k_gather(const unsigned short* __restrict__ Hf, const unsigned short* __restrict__ csr,
              const float* __restrict__ dis, const int* __restrict__ offs,
              unsigned short* __restrict__ Agg){
  int lane = threadIdx.x & 63;
  int node = blockIdx.x*4 + (threadIdx.x >> 6);
  int half = lane >> 5;
  int q4 = (lane & 31)*4;
  int start = offs[node];
  int n = offs[node+1] - start;
  float dn = dis[node];
  float ax = 0.f, ay = 0.f, az = 0.f, aw = 0.f;
  for (int k = half; k < n; k += 2){
    int e = start + k;
    int s = csr[e];
    float nv = dis[s];                    // broadcast load within half-wave
    ushort4 u = *reinterpret_cast<const ushort4*>(Hf + s*128 + q4);
    ax = fmaf(bf2f(u.x), nv, ax); ay = fmaf(bf2f(u.y), nv, ay);
    az = fmaf(bf2f(u.z), nv, az); aw = fmaf(bf2f(u.w), nv, aw);
  }
  ax += __shfl_xor(ax, 32); ay += __shfl_xor(ay, 32);
  az += __shfl_xor(az, 32); aw += __shfl_xor(aw, 32);
  if (half == 0){
    ushort4 o;
    o.x = f2bf(ax*dn); o.y = f2bf(ay*dn); o.z = f2bf(az*dn); o.w = f2bf(aw*dn);
    *reinterpret_cast<ushort4*>(Agg + node*128 + q4) = o;
  }
}

// C = relu(bn((X @ W^T) + bias)) -> bf16;  MODE 1: X fp32, Jk = C;  MODE 2: X bf16, Jk = max(Jk, C).
template<int MODE>
__global__ __launch_bounds__(512, 4)
void k_gemm(const float* __restrict__ Xf, const unsigned short* __restrict__ Xb,
            const float* __restrict__ Wt, const float* __restrict__ bias,
            const float* __restrict__ gamma, const float* __restrict__ beta,
            unsigned short* __restrict__ Cout, float* __restrict__ Jk){
  __shared__ float Bs[128][128];
  const int t = threadIdx.x;
  {
    const float4* src = reinterpret_cast<const float4*>(Wt);
    float4* dst = reinterpret_cast<float4*>(&Bs[0][0]);
    #pragma unroll
    for (int it = 0; it < 8; ++it) dst[it*512 + t] = src[it*512 + t];
  }
  __syncthreads();
  const int c4 = (t & 31)*4;
  const int tr = t >> 5;
  const int m0 = blockIdx.x*128 + tr*4;
  int off[8];
  #pragma unroll
  for (int r = 0; r < 8; ++r){
    int m = m0 + (r & 3) + (r >> 2)*64;
    off[r] = (m < NN ? m : 0)*128;   // clamp OOB rows; store is guarded below
  }
  float acc[8][4] = {};
  for (int kk = 0; kk < 128; kk += 4){
    float b[4][4];
    #pragma unroll
    for (int j = 0; j < 4; ++j){
      float4 v = ld4(&Bs[kk+j][c4]);
      b[j][0] = v.x; b[j][1] = v.y; b[j][2] = v.z; b[j][3] = v.w;
    }
    #pragma unroll
    for (int r = 0; r < 8; ++r){
      float4 v;
      if constexpr (MODE == 1){
        v = ld4(Xf + off[r] + kk);
      } else {
        ushort4 u = *reinterpret_cast<const ushort4*>(Xb + off[r] + kk);
        v.x = bf2f(u.x); v.y = bf2f(u.y); v.z = bf2f(u.z); v.w = bf2f(u.w);
      }
      #pragma unroll
      for (int q = 0; q < 4; ++q){
        acc[r][q] = fmaf(v.x, b[0][q], acc[r][q]);
        acc[r][q] = fmaf(v.y, b[1][q], acc[r][q]);
        acc[r][q] = fmaf(v.z, b[2][q], acc[r][q]);
        acc[r][q] = fmaf(v.w, b[3][q], acc[r][q]);
      }
    }
  }
  float4 bi = ld4(bias + c4);
  float4 g  = ld4(gamma + c4);
  float4 be = ld4(beta + c4);
  float sc0 = g.x*BN_SC, sc1 = g.y*BN_SC, sc2 = g.z*BN_SC, sc3 = g.w*BN_SC;
  #pragma unroll
  for (int r = 0; r < 8; ++r){
    int m = m0 + (r & 3) + (r >> 2)*64;
    if (m < NN){
      float4 o;
      o.x = fmaxf(fmaf(acc[r][0] + bi.x, sc0, be.x), 0.f);
      o.y = fmaxf(fmaf(acc[r][1] + bi.y, sc1, be.y), 0.f);
      o.z = fmaxf(fmaf(acc[r][2] + bi.z, sc2, be.z), 0.f);
      o.w = fmaxf(fmaf(acc[r][3] + bi.w, sc3, be.w), 0.f);
      ushort4 ob;
      ob.x = f2bf(o.x); ob.y = f2bf(o.y); ob.z = f2bf(o.z); ob.w = f2bf(o.w);
      *reinterpret_cast<ushort4*>(Cout + m*128 + c4) = ob;
      if (MODE == 1){
        st4(Jk + m*128 + c4, o);
      } else {
        float4 jo = ld4(Jk + m*128 + c4);
        float4 nj;
        nj.x = fmaxf(jo.x, o.x); nj.y = fmaxf(jo.y, o.y);
        nj.z = fmaxf(jo.z, o.z); nj.w = fmaxf(jo.w, o.w);
        st4(Jk + m*128 + c4, nj);
      }
    }
  }
}

// Out[m][c] = X[m] . WfT[:][c] + bf[c]   (C=40), BM=128, 128 threads, 8x5 acc
__global__ __launch_bounds__(128)
void k_gemm_final(const float* __restrict__ X, const float* __restrict__ WfT,
                  const float* __restrict__ bf, float* __restrict__ Out){
  __shared__ float Bs[5120];
  const int t = threadIdx.x;
  #pragma unroll
  for (int it = 0; it < 40; ++it) Bs[it*128 + t] = WfT[it*128 + t];
  __syncthreads();
  const int cg = (t & 7)*5;
  const int tr = t >> 3;
  const int m0 = blockIdx.x*128 + tr*4;
  int off[8];
  #pragma unroll
  for (int r = 0; r < 8; ++r){
    int m = m0 + (r & 3) + (r >> 2)*64;
    off[r] = (m < NN ? m : 0)*128;
  }
  float acc[8][5] = {};
  for (int kk = 0; kk < 128; kk += 4){
    float b[4][5];
    #pragma unroll
    for (int j = 0; j < 4; ++j)
      #pragma unroll
      for (int q = 0; q < 5; ++q)
        b[j][q] = Bs[(kk+j)*40 + cg + q];
    #pragma unroll
    for (int r = 0; r < 8; ++r){
      float4 v = ld4(X + off[r] + kk);
      #pragma unroll
      for (int q = 0; q < 5; ++q){
        acc[r][q] = fmaf(v.x, b[0][q], acc[r][q]);
        acc[r][q] = fmaf(v.y, b[1][q], acc[r][q]);
        acc[r][q] = fmaf(v.z, b[2][q], acc[r][q]);
        acc[r][q] = fmaf(v.w, b[3][q], acc[r][q]);
      }
    }
  }
  float bb[5];
  #pragma unroll
  for (int q = 0; q < 5; ++q) bb[q] = bf[cg + q];
  #pragma unroll
  for (int r = 0; r < 8; ++r){
    int m = m0 + (r & 3) + (r >> 2)*64;
    if (m < NN){
      #pragma unroll
      for (int q = 0; q < 5; ++q) Out[m*40 + cg + q] = acc[r][q] + bb[q];
    }
  }
}

extern "C" void kernel_launch(void* const* d_in, const int* in_sizes, int n_in,
                              void* d_out, int out_size, void* d_ws, size_t ws_size,
                              hipStream_t stream){
  const float* x     = (const float*)d_in[0];
  const int*   ei    = (const int*)d_in[1];
  const float* fc0_w = (const float*)d_in[2];
  const float* fc0_b = (const float*)d_in[3];
  const float* convw = (const float*)d_in[4];
  const float* Ww    = (const float*)d_in[5];
  const float* Wb    = (const float*)d_in[6];
  const float* bng   = (const float*)d_in[7];
  const float* bnb   = (const float*)d_in[8];
  const float* fow   = (const float*)d_in[9];
  const float* fob   = (const float*)d_in[10];
  const float* outw  = (const float*)d_in[11];
  const float* outb  = (const float*)d_in[12];
  float* out = (float*)d_out;

  char* p = (char*)d_ws;
  auto alloc = [&](size_t n){ char* r = p; p += (n + 255) & ~(size_t)255; return r; };
  int*   gbucket = (int*)  alloc((size_t)NB*4);
  int*   ebase   = (int*)  alloc((size_t)(NB+1)*4);
  int*   tbase   = (int*)  alloc((size_t)(NB+1)*4);
  int*   gcur    = (int*)  alloc((size_t)NB*4);
  unsigned int*   bbuf  = (unsigned int*)  alloc((size_t)NE*4);
  unsigned short* csr16 = (unsigned short*)alloc((size_t)EN*2);
  int*   offs    = (int*)  alloc((size_t)(NN+1)*4);
  float* dis     = (float*)alloc((size_t)NN*4);
  float* Wt0     = (float*)alloc(16384*4);
  float* WCt0    = (float*)alloc(16384*4);
  float* WCt1    = (float*)alloc(16384*4);
  float* WfT     = (float*)alloc(5120*4);
  float* bf      = (float*)alloc(64*4);
  unsigned short* H1  = (unsigned short*)alloc((size_t)NN*128*2);
  unsigned short* AGG = (unsigned short*)alloc((size_t)NN*128*2);
  float* JKb     = (float*)alloc((size_t)NN*128*4);

  hipMemsetAsync(gbucket, 0, (size_t)NB*4, stream);
  k_bhist<<<BINBLK, 256, 0, stream>>>(ei, gbucket);
  k_bscan<<<1, 64, 0, stream>>>(gbucket, ebase, tbase, gcur);
  k_bin<<<BINBLK, 256, 0, stream>>>(ei, gcur, bbuf);
  k_csr<<<NB, 256, 0, stream>>>(bbuf, ebase, tbase, csr16, offs, dis);
  k_wprep<<<212, 256, 0, stream>>>(fc0_w, Ww, convw, outw, fow, fob, outb,
                                   Wt0, WCt0, WCt1, WfT, bf);

  k_gemm<1><<<391, 512, 0, stream>>>(x, nullptr, Wt0, fc0_b, bng, bnb, H1, JKb);
  k_gather<<<12500, 256, 0, stream>>>(H1, csr16, dis, offs, AGG);
  k_gemm<2><<<391, 512, 0, stream>>>(nullptr, AGG, WCt0, Wb, bng + 128, bnb + 128, H1, JKb);
  k_gather<<<12500, 256, 0, stream>>>(H1, csr16, dis, offs, AGG);
  k_gemm<2><<<391, 512, 0, stream>>>(nullptr, AGG, WCt1, Wb, bng + 256, bnb + 256, H1, JKb);
  k_gemm_final<<<391, 128, 0, stream>>>(JKb, WfT, bf, out);
}

// Round 5
// 295.459 us; speedup vs baseline: 1.4141x; 1.0981x over previous
//
#include <hip/hip_runtime.h>

#define NN 50000
#define NE 800000
#define EN 850000
#define NB 196       // dst buckets of 256 nodes
#define BINBLK 391   // ceil(NE/2048)

static constexpr float BN_SC = 0.99999500003749968f; // 1/sqrt(1+1e-5)

__device__ __forceinline__ float4 ld4(const float* p){ return *reinterpret_cast<const float4*>(p); }
__device__ __forceinline__ void st4(float* p, float4 v){ *reinterpret_cast<float4*>(p) = v; }

__device__ __forceinline__ float bf2f(unsigned short u){
  union { unsigned int i; float f; } v; v.i = ((unsigned int)u) << 16; return v.f;
}
__device__ __forceinline__ unsigned short f2bf(float f){
  union { float f; unsigned int i; } v; v.f = f;
  unsigned int r = v.i + 0x7fffu + ((v.i >> 16) & 1u);   // RNE
  return (unsigned short)(r >> 16);
}
__device__ __forceinline__ float lo2f(unsigned int u){
  union { unsigned int i; float f; } v; v.i = u << 16; return v.f;
}
__device__ __forceinline__ float hi2f(unsigned int u){
  union { unsigned int i; float f; } v; v.i = u & 0xffff0000u; return v.f;
}
__device__ __forceinline__ unsigned int pk2(float flo, float fhi){
  return (unsigned int)f2bf(flo) | ((unsigned int)f2bf(fhi) << 16);
}

// ---- Level-0: per-bucket edge histogram (LDS-privatized) ----
extern "C" __global__ __launch_bounds__(256)
void k_bhist(const int* __restrict__ ei, int* __restrict__ gbucket){
  __shared__ int h[NB];
  int t = threadIdx.x;
  if (t < NB) h[t] = 0;
  __syncthreads();
  int e0 = blockIdx.x*2048;
  for (int i = t; i < 2048; i += 256){
    int e = e0 + i;
    if (e < NE) atomicAdd(&h[ei[NE+e] >> 8], 1);
  }
  __syncthreads();
  if (t < NB && h[t] > 0) atomicAdd(&gbucket[t], h[t]);
}

// ---- bucket base offsets (edge-only and with analytic self-loops) ----
extern "C" __global__ void k_bscan(const int* __restrict__ gbucket, int* __restrict__ ebase,
                                   int* __restrict__ tbase, int* __restrict__ gcur){
  if (threadIdx.x == 0){
    int runE = 0, runT = 0;
    for (int b = 0; b < NB; ++b){
      int ge = gbucket[b];
      int sc = (b < NB-1) ? 256 : (NN - (NB-1)*256);
      ebase[b] = runE; gcur[b] = runE; tbase[b] = runT;
      runE += ge; runT += ge + sc;
    }
    ebase[NB] = runE; tbase[NB] = runT;
  }
}

// ---- Level-1: bin edges by bucket; LDS-staged, run-coalesced flush ----
extern "C" __global__ __launch_bounds__(256)
void k_bin(const int* __restrict__ ei, int* __restrict__ gcur, unsigned int* __restrict__ bbuf){
  __shared__ int h[NB], lbase[NB], gbase[NB];
  __shared__ int tot;
  __shared__ unsigned int stage[2048];
  __shared__ unsigned char bid[2048];
  int t = threadIdx.x;
  if (t < NB) h[t] = 0;
  __syncthreads();
  int e0 = blockIdx.x*2048;
  for (int i = t; i < 2048; i += 256){
    int e = e0 + i;
    if (e < NE) atomicAdd(&h[ei[NE+e] >> 8], 1);
  }
  __syncthreads();
  if (t == 0){
    int run = 0;
    for (int b = 0; b < NB; ++b){ lbase[b] = run; run += h[b]; }
    tot = run;
  }
  __syncthreads();
  if (t < NB && h[t] > 0) gbase[t] = atomicAdd(&gcur[t], h[t]);  // one atomic per (block,bucket)
  __syncthreads();
  if (t < NB) h[t] = lbase[t];      // reuse as LDS placement cursor
  __syncthreads();
  for (int i = t; i < 2048; i += 256){
    int e = e0 + i;
    if (e < NE){
      int s = ei[e], d = ei[NE+e];
      int b = d >> 8;
      int p = atomicAdd(&h[b], 1);
      stage[p] = ((unsigned int)d << 16) | (unsigned int)s;   // node ids < 2^16
      bid[p] = (unsigned char)b;
    }
  }
  __syncthreads();
  int m = tot;
  for (int j = t; j < m; j += 256){
    int b = bid[j];
    bbuf[gbase[b] + (j - lbase[b])] = stage[j];               // contiguous per-bucket runs
  }
}

// ---- Level-2: per-bucket counting sort -> final CSR (u16 src), offs, dis ----
extern "C" __global__ __launch_bounds__(256)
void k_csr(const unsigned int* __restrict__ bbuf, const int* __restrict__ ebase,
           const int* __restrict__ tbase, unsigned short* __restrict__ csr,
           int* __restrict__ offs, float* __restrict__ dis){
  __shared__ int h[256], loff[256], lcur[256];
  __shared__ unsigned short stage[8192];
  int t = threadIdx.x;
  int b = blockIdx.x;
  int nb0 = b << 8;
  int BNv = min(256, NN - nb0);
  int ebeg = ebase[b];
  int m = ebase[b+1] - ebeg;
  int base = tbase[b];
  h[t] = (t < BNv) ? 1 : 0;    // self-loop
  __syncthreads();
  for (int i = t; i < m; i += 256)
    atomicAdd(&h[(bbuf[ebeg + i] >> 16) & 255], 1);
  __syncthreads();
  if (t == 0){
    int run = 0;
    for (int n = 0; n < BNv; ++n){ loff[n] = run; run += h[n]; }
  }
  __syncthreads();
  if (t < BNv){
    offs[nb0 + t] = base + loff[t];
    dis[nb0 + t] = rsqrtf((float)h[t]);
    lcur[t] = loff[t] + 1;
    stage[loff[t]] = (unsigned short)(nb0 + t);   // self-loop edge first
  }
  if (b == NB-1 && t == 0) offs[NN] = EN;
  __syncthreads();
  for (int i = t; i < m; i += 256){
    unsigned int e = bbuf[ebeg + i];
    int p = atomicAdd(&lcur[(e >> 16) & 255], 1);
    stage[p] = (unsigned short)(e & 0xffffu);
  }
  __syncthreads();
  int M = m + BNv;
  for (int j = t; j < M; j += 256) csr[base + j] = stage[j];  // fully coalesced
}

// Fused weight prep, dispatched by blockIdx range.
extern "C" __global__ void k_wprep(const float* __restrict__ fc0_w,
                                   const float* __restrict__ Ww, const float* __restrict__ cw,
                                   const float* __restrict__ ow, const float* __restrict__ fw,
                                   const float* __restrict__ fb, const float* __restrict__ ob,
                                   float* __restrict__ Wt0, float* __restrict__ WCt0,
                                   float* __restrict__ WCt1, float* __restrict__ WfT,
                                   float* __restrict__ bf){
  int b = blockIdx.x;
  if (b < 64){
    int idx = b*256 + threadIdx.x;
    int f = idx >> 7, k = idx & 127;
    Wt0[k*128 + f] = fc0_w[f*128 + k];
  } else if (b < 192){
    int idx = (b & 63)*256 + threadIdx.x;
    int f = idx >> 7, k = idx & 127;
    const float* c = (b < 128) ? cw : (cw + 16384);
    float acc = 0.f;
    #pragma unroll 4
    for (int j = 0; j < 128; ++j) acc = fmaf(Ww[f*128 + j], c[j*128 + k], acc);
    float* o = (b < 128) ? WCt0 : WCt1;
    o[k*128 + f] = acc;
  } else {
    int idx = (b - 192)*256 + threadIdx.x;
    if (idx < 5120){
      int c = idx >> 7, k = idx & 127;
      float acc = 0.f;
      for (int j = 0; j < 128; ++j) acc = fmaf(ow[c*128 + j], fw[j*128 + k], acc);
      WfT[k*40 + c] = acc;
    }
    if (idx < 40){
      float acc = ob[idx];
      for (int j = 0; j < 128; ++j) acc = fmaf(ow[idx*128 + j], fb[j], acc);
      bf[idx] = acc;
    }
  }
}

// Agg[n] = dis[n] * sum_e dis[s_e] * Hf[s_e]
// One wave per node; 4 groups x 16 lanes (uint4 = 16B/lane = full 256B row per group);
// unroll x2 -> 8 independent row loads in flight. Tail via clamp + zero weight (no divergence).
extern "C" __global__ __launch_bounds__(256)
void k_gather(const unsigned short* __restrict__ Hf, const unsigned short* __restrict__ csr,
              const float* __restrict__ dis, const int* __restrict__ offs,
              unsigned short* __restrict__ Agg){
  int lane = threadIdx.x & 63;
  int node = blockIdx.x*4 + (threadIdx.x >> 6);
  int grp  = lane >> 4;          // 0..3
  int q8   = (lane & 15)*8;      // 8 bf16 features per lane
  int start = offs[node];
  int n = offs[node+1] - start;  // >= 1 (self-loop)
  float dn = dis[node];
  float a0=0,a1=0,a2=0,a3=0,a4=0,a5=0,a6=0,a7=0;
  int nm1 = n - 1;
  for (int i = 0; i < n; i += 8){
    int k0 = i + grp;
    int k1 = i + 4 + grp;
    int c0 = (k0 < n) ? k0 : nm1;
    int c1 = (k1 < n) ? k1 : nm1;
    int s0 = csr[start + c0];
    int s1 = csr[start + c1];
    float w0 = (k0 < n) ? dis[s0] : 0.f;
    float w1 = (k1 < n) ? dis[s1] : 0.f;
    uint4 u0 = *reinterpret_cast<const uint4*>(Hf + s0*128 + q8);
    uint4 u1 = *reinterpret_cast<const uint4*>(Hf + s1*128 + q8);
    a0 = fmaf(lo2f(u0.x), w0, a0); a1 = fmaf(hi2f(u0.x), w0, a1);
    a2 = fmaf(lo2f(u0.y), w0, a2); a3 = fmaf(hi2f(u0.y), w0, a3);
    a4 = fmaf(lo2f(u0.z), w0, a4); a5 = fmaf(hi2f(u0.z), w0, a5);
    a6 = fmaf(lo2f(u0.w), w0, a6); a7 = fmaf(hi2f(u0.w), w0, a7);
    a0 = fmaf(lo2f(u1.x), w1, a0); a1 = fmaf(hi2f(u1.x), w1, a1);
    a2 = fmaf(lo2f(u1.y), w1, a2); a3 = fmaf(hi2f(u1.y), w1, a3);
    a4 = fmaf(lo2f(u1.z), w1, a4); a5 = fmaf(hi2f(u1.z), w1, a5);
    a6 = fmaf(lo2f(u1.w), w1, a6); a7 = fmaf(hi2f(u1.w), w1, a7);
  }
  a0 += __shfl_xor(a0, 16); a1 += __shfl_xor(a1, 16);
  a2 += __shfl_xor(a2, 16); a3 += __shfl_xor(a3, 16);
  a4 += __shfl_xor(a4, 16); a5 += __shfl_xor(a5, 16);
  a6 += __shfl_xor(a6, 16); a7 += __shfl_xor(a7, 16);
  a0 += __shfl_xor(a0, 32); a1 += __shfl_xor(a1, 32);
  a2 += __shfl_xor(a2, 32); a3 += __shfl_xor(a3, 32);
  a4 += __shfl_xor(a4, 32); a5 += __shfl_xor(a5, 32);
  a6 += __shfl_xor(a6, 32); a7 += __shfl_xor(a7, 32);
  if (grp == 0){
    uint4 o;
    o.x = pk2(a0*dn, a1*dn);
    o.y = pk2(a2*dn, a3*dn);
    o.z = pk2(a4*dn, a5*dn);
    o.w = pk2(a6*dn, a7*dn);
    *reinterpret_cast<uint4*>(Agg + node*128 + q8) = o;
  }
}

// C = relu(bn((X @ W^T) + bias)) -> bf16;  MODE 1: X fp32, Jk = C;  MODE 2: X bf16, Jk = max(Jk, C).
template<int MODE>
__global__ __launch_bounds__(512, 4)
void k_gemm(const float* __restrict__ Xf, const unsigned short* __restrict__ Xb,
            const float* __restrict__ Wt, const float* __restrict__ bias,
            const float* __restrict__ gamma, const float* __restrict__ beta,
            unsigned short* __restrict__ Cout, float* __restrict__ Jk){
  __shared__ float Bs[128][128];
  const int t = threadIdx.x;
  {
    const float4* src = reinterpret_cast<const float4*>(Wt);
    float4* dst = reinterpret_cast<float4*>(&Bs[0][0]);
    #pragma unroll
    for (int it = 0; it < 8; ++it) dst[it*512 + t] = src[it*512 + t];
  }
  __syncthreads();
  const int c4 = (t & 31)*4;
  const int tr = t >> 5;
  const int m0 = blockIdx.x*128 + tr*4;
  int off[8];
  #pragma unroll
  for (int r = 0; r < 8; ++r){
    int m = m0 + (r & 3) + (r >> 2)*64;
    off[r] = (m < NN ? m : 0)*128;   // clamp OOB rows; store is guarded below
  }
  float acc[8][4] = {};
  for (int kk = 0; kk < 128; kk += 4){
    float b[4][4];
    #pragma unroll
    for (int j = 0; j < 4; ++j){
      float4 v = ld4(&Bs[kk+j][c4]);
      b[j][0] = v.x; b[j][1] = v.y; b[j][2] = v.z; b[j][3] = v.w;
    }
    #pragma unroll
    for (int r = 0; r < 8; ++r){
      float4 v;
      if constexpr (MODE == 1){
        v = ld4(Xf + off[r] + kk);
      } else {
        ushort4 u = *reinterpret_cast<const ushort4*>(Xb + off[r] + kk);
        v.x = bf2f(u.x); v.y = bf2f(u.y); v.z = bf2f(u.z); v.w = bf2f(u.w);
      }
      #pragma unroll
      for (int q = 0; q < 4; ++q){
        acc[r][q] = fmaf(v.x, b[0][q], acc[r][q]);
        acc[r][q] = fmaf(v.y, b[1][q], acc[r][q]);
        acc[r][q] = fmaf(v.z, b[2][q], acc[r][q]);
        acc[r][q] = fmaf(v.w, b[3][q], acc[r][q]);
      }
    }
  }
  float4 bi = ld4(bias + c4);
  float4 g  = ld4(gamma + c4);
  float4 be = ld4(beta + c4);
  float sc0 = g.x*BN_SC, sc1 = g.y*BN_SC, sc2 = g.z*BN_SC, sc3 = g.w*BN_SC;
  #pragma unroll
  for (int r = 0; r < 8; ++r){
    int m = m0 + (r & 3) + (r >> 2)*64;
    if (m < NN){
      float4 o;
      o.x = fmaxf(fmaf(acc[r][0] + bi.x, sc0, be.x), 0.f);
      o.y = fmaxf(fmaf(acc[r][1] + bi.y, sc1, be.y), 0.f);
      o.z = fmaxf(fmaf(acc[r][2] + bi.z, sc2, be.z), 0.f);
      o.w = fmaxf(fmaf(acc[r][3] + bi.w, sc3, be.w), 0.f);
      ushort4 ob;
      ob.x = f2bf(o.x); ob.y = f2bf(o.y); ob.z = f2bf(o.z); ob.w = f2bf(o.w);
      *reinterpret_cast<ushort4*>(Cout + m*128 + c4) = ob;
      if (MODE == 1){
        st4(Jk + m*128 + c4, o);
      } else {
        float4 jo = ld4(Jk + m*128 + c4);
        float4 nj;
        nj.x = fmaxf(jo.x, o.x); nj.y = fmaxf(jo.y, o.y);
        nj.z = fmaxf(jo.z, o.z); nj.w = fmaxf(jo.w, o.w);
        st4(Jk + m*128 + c4, nj);
      }
    }
  }
}

// Out[m][c] = X[m] . WfT[:][c] + bf[c]   (C=40), BM=128, 128 threads, 8x5 acc
__global__ __launch_bounds__(128)
void k_gemm_final(const float* __restrict__ X, const float* __restrict__ WfT,
                  const float* __restrict__ bf, float* __restrict__ Out){
  __shared__ float Bs[5120];
  const int t = threadIdx.x;
  #pragma unroll
  for (int it = 0; it < 40; ++it) Bs[it*128 + t] = WfT[it*128 + t];
  __syncthreads();
  const int cg = (t & 7)*5;
  const int tr = t >> 3;
  const int m0 = blockIdx.x*128 + tr*4;
  int off[8];
  #pragma unroll
  for (int r = 0; r < 8; ++r){
    int m = m0 + (r & 3) + (r >> 2)*64;
    off[r] = (m < NN ? m : 0)*128;
  }
  float acc[8][5] = {};
  for (int kk = 0; kk < 128; kk += 4){
    float b[4][5];
    #pragma unroll
    for (int j = 0; j < 4; ++j)
      #pragma unroll
      for (int q = 0; q < 5; ++q)
        b[j][q] = Bs[(kk+j)*40 + cg + q];
    #pragma unroll
    for (int r = 0; r < 8; ++r){
      float4 v = ld4(X + off[r] + kk);
      #pragma unroll
      for (int q = 0; q < 5; ++q){
        acc[r][q] = fmaf(v.x, b[0][q], acc[r][q]);
        acc[r][q] = fmaf(v.y, b[1][q], acc[r][q]);
        acc[r][q] = fmaf(v.z, b[2][q], acc[r][q]);
        acc[r][q] = fmaf(v.w, b[3][q], acc[r][q]);
      }
    }
  }
  float bb[5];
  #pragma unroll
  for (int q = 0; q < 5; ++q) bb[q] = bf[cg + q];
  #pragma unroll
  for (int r = 0; r < 8; ++r){
    int m = m0 + (r & 3) + (r >> 2)*64;
    if (m < NN){
      #pragma unroll
      for (int q = 0; q < 5; ++q) Out[m*40 + cg + q] = acc[r][q] + bb[q];
    }
  }
}

extern "C" void kernel_launch(void* const* d_in, const int* in_sizes, int n_in,
                              void* d_out, int out_size, void* d_ws, size_t ws_size,
                              hipStream_t stream){
  const float* x     = (const float*)d_in[0];
  const int*   ei    = (const int*)d_in[1];
  const float* fc0_w = (const float*)d_in[2];
  const float* fc0_b = (const float*)d_in[3];
  const float* convw = (const float*)d_in[4];
  const float* Ww    = (const float*)d_in[5];
  const float* Wb    = (const float*)d_in[6];
  const float* bng   = (const float*)d_in[7];
  const float* bnb   = (const float*)d_in[8];
  const float* fow   = (const float*)d_in[9];
  const float* fob   = (const float*)d_in[10];
  const float* outw  = (const float*)d_in[11];
  const float* outb  = (const float*)d_in[12];
  float* out = (float*)d_out;

  char* p = (char*)d_ws;
  auto alloc = [&](size_t n){ char* r = p; p += (n + 255) & ~(size_t)255; return r; };
  int*   gbucket = (int*)  alloc((size_t)NB*4);
  int*   ebase   = (int*)  alloc((size_t)(NB+1)*4);
  int*   tbase   = (int*)  alloc((size_t)(NB+1)*4);
  int*   gcur    = (int*)  alloc((size_t)NB*4);
  unsigned int*   bbuf  = (unsigned int*)  alloc((size_t)NE*4);
  unsigned short* csr16 = (unsigned short*)alloc((size_t)EN*2);
  int*   offs    = (int*)  alloc((size_t)(NN+1)*4);
  float* dis     = (float*)alloc((size_t)NN*4);
  float* Wt0     = (float*)alloc(16384*4);
  float* WCt0    = (float*)alloc(16384*4);
  float* WCt1    = (float*)alloc(16384*4);
  float* WfT     = (float*)alloc(5120*4);
  float* bf      = (float*)alloc(64*4);
  unsigned short* H1  = (unsigned short*)alloc((size_t)NN*128*2);
  unsigned short* AGG = (unsigned short*)alloc((size_t)NN*128*2);
  float* JKb     = (float*)alloc((size_t)NN*128*4);

  hipMemsetAsync(gbucket, 0, (size_t)NB*4, stream);
  k_bhist<<<BINBLK, 256, 0, stream>>>(ei, gbucket);
  k_bscan<<<1, 64, 0, stream>>>(gbucket, ebase, tbase, gcur);
  k_bin<<<BINBLK, 256, 0, stream>>>(ei, gcur, bbuf);
  k_csr<<<NB, 256, 0, stream>>>(bbuf, ebase, tbase, csr16, offs, dis);
  k_wprep<<<212, 256, 0, stream>>>(fc0_w, Ww, convw, outw, fow, fob, outb,
                                   Wt0, WCt0, WCt1, WfT, bf);

  k_gemm<1><<<391, 512, 0, stream>>>(x, nullptr, Wt0, fc0_b, bng, bnb, H1, JKb);
  k_gather<<<12500, 256, 0, stream>>>(H1, csr16, dis, offs, AGG);
  k_gemm<2><<<391, 512, 0, stream>>>(nullptr, AGG, WCt0, Wb, bng + 128, bnb + 128, H1, JKb);
  k_gather<<<12500, 256, 0, stream>>>(H1, csr16, dis, offs, AGG);
  k_gemm<2><<<391, 512, 0, stream>>>(nullptr, AGG, WCt1, Wb, bng + 256, bnb + 256, H1, JKb);
  k_gemm_final<<<391, 128, 0, stream>>>(JKb, WfT, bf, out);
}

// Round 6
// 197.071 us; speedup vs baseline: 2.1201x; 1.4992x over previous
//
#include <hip/hip_runtime.h>

#define NN 50000
#define NE 800000
#define EN 850000
#define NB 196       // dst buckets of 256 nodes
#define BINBLK 391   // ceil(NE/2048)

static constexpr float BN_SC = 0.99999500003749968f; // 1/sqrt(1+1e-5)

typedef __bf16 bf16x8 __attribute__((ext_vector_type(8)));
typedef float  f32x4  __attribute__((ext_vector_type(4)));

__device__ __forceinline__ float4 ld4(const float* p){ return *reinterpret_cast<const float4*>(p); }

__device__ __forceinline__ float bf2f(unsigned short u){
  union { unsigned int i; float f; } v; v.i = ((unsigned int)u) << 16; return v.f;
}
__device__ __forceinline__ unsigned short f2bf(float f){
  union { float f; unsigned int i; } v; v.f = f;
  unsigned int r = v.i + 0x7fffu + ((v.i >> 16) & 1u);   // RNE
  return (unsigned short)(r >> 16);
}
__device__ __forceinline__ float lo2f(unsigned int u){
  union { unsigned int i; float f; } v; v.i = u << 16; return v.f;
}
__device__ __forceinline__ float hi2f(unsigned int u){
  union { unsigned int i; float f; } v; v.i = u & 0xffff0000u; return v.f;
}
__device__ __forceinline__ unsigned int pk2(float flo, float fhi){
  return (unsigned int)f2bf(flo) | ((unsigned int)f2bf(fhi) << 16);
}
// frag-linear index for B-operand element (n, k) of a 128-wide K matrix
__device__ __forceinline__ int fragidx(int n, int k){
  int nt = n >> 4, c = n & 15, ks = k >> 5, g = (k >> 3) & 3, j = k & 7;
  return ((nt*4 + ks)*64 + g*16 + c)*8 + j;
}

// ---- Level-0: per-bucket edge histogram (LDS-privatized) ----
extern "C" __global__ __launch_bounds__(256)
void k_bhist(const int* __restrict__ ei, int* __restrict__ gbucket){
  __shared__ int h[NB];
  int t = threadIdx.x;
  if (t < NB) h[t] = 0;
  __syncthreads();
  int e0 = blockIdx.x*2048;
  for (int i = t; i < 2048; i += 256){
    int e = e0 + i;
    if (e < NE) atomicAdd(&h[ei[NE+e] >> 8], 1);
  }
  __syncthreads();
  if (t < NB && h[t] > 0) atomicAdd(&gbucket[t], h[t]);
}

// ---- bucket base offsets (edge-only and with analytic self-loops) ----
extern "C" __global__ void k_bscan(const int* __restrict__ gbucket, int* __restrict__ ebase,
                                   int* __restrict__ tbase, int* __restrict__ gcur){
  if (threadIdx.x == 0){
    int runE = 0, runT = 0;
    for (int b = 0; b < NB; ++b){
      int ge = gbucket[b];
      int sc = (b < NB-1) ? 256 : (NN - (NB-1)*256);
      ebase[b] = runE; gcur[b] = runE; tbase[b] = runT;
      runE += ge; runT += ge + sc;
    }
    ebase[NB] = runE; tbase[NB] = runT;
  }
}

// ---- Level-1: bin edges by bucket; LDS-staged, run-coalesced flush ----
extern "C" __global__ __launch_bounds__(256)
void k_bin(const int* __restrict__ ei, int* __restrict__ gcur, unsigned int* __restrict__ bbuf){
  __shared__ int h[NB], lbase[NB], gbase[NB];
  __shared__ int tot;
  __shared__ unsigned int stage[2048];
  __shared__ unsigned char bid[2048];
  int t = threadIdx.x;
  if (t < NB) h[t] = 0;
  __syncthreads();
  int e0 = blockIdx.x*2048;
  for (int i = t; i < 2048; i += 256){
    int e = e0 + i;
    if (e < NE) atomicAdd(&h[ei[NE+e] >> 8], 1);
  }
  __syncthreads();
  if (t == 0){
    int run = 0;
    for (int b = 0; b < NB; ++b){ lbase[b] = run; run += h[b]; }
    tot = run;
  }
  __syncthreads();
  if (t < NB && h[t] > 0) gbase[t] = atomicAdd(&gcur[t], h[t]);  // one atomic per (block,bucket)
  __syncthreads();
  if (t < NB) h[t] = lbase[t];      // reuse as LDS placement cursor
  __syncthreads();
  for (int i = t; i < 2048; i += 256){
    int e = e0 + i;
    if (e < NE){
      int s = ei[e], d = ei[NE+e];
      int b = d >> 8;
      int p = atomicAdd(&h[b], 1);
      stage[p] = ((unsigned int)d << 16) | (unsigned int)s;   // node ids < 2^16
      bid[p] = (unsigned char)b;
    }
  }
  __syncthreads();
  int m = tot;
  for (int j = t; j < m; j += 256){
    int b = bid[j];
    bbuf[gbase[b] + (j - lbase[b])] = stage[j];               // contiguous per-bucket runs
  }
}

// ---- Level-2: per-bucket counting sort -> final CSR (u16 src), offs, dis ----
extern "C" __global__ __launch_bounds__(256)
void k_csr(const unsigned int* __restrict__ bbuf, const int* __restrict__ ebase,
           const int* __restrict__ tbase, unsigned short* __restrict__ csr,
           int* __restrict__ offs, float* __restrict__ dis){
  __shared__ int h[256], loff[256], lcur[256];
  __shared__ unsigned short stage[8192];
  int t = threadIdx.x;
  int b = blockIdx.x;
  int nb0 = b << 8;
  int BNv = min(256, NN - nb0);
  int ebeg = ebase[b];
  int m = ebase[b+1] - ebeg;
  int base = tbase[b];
  h[t] = (t < BNv) ? 1 : 0;    // self-loop
  __syncthreads();
  for (int i = t; i < m; i += 256)
    atomicAdd(&h[(bbuf[ebeg + i] >> 16) & 255], 1);
  __syncthreads();
  if (t == 0){
    int run = 0;
    for (int n = 0; n < BNv; ++n){ loff[n] = run; run += h[n]; }
  }
  __syncthreads();
  if (t < BNv){
    offs[nb0 + t] = base + loff[t];
    dis[nb0 + t] = rsqrtf((float)h[t]);
    lcur[t] = loff[t] + 1;
    stage[loff[t]] = (unsigned short)(nb0 + t);   // self-loop edge first
  }
  if (b == NB-1 && t == 0) offs[NN] = EN;
  __syncthreads();
  for (int i = t; i < m; i += 256){
    unsigned int e = bbuf[ebeg + i];
    int p = atomicAdd(&lcur[(e >> 16) & 255], 1);
    stage[p] = (unsigned short)(e & 0xffffu);
  }
  __syncthreads();
  int M = m + BNv;
  for (int j = t; j < M; j += 256) csr[base + j] = stage[j];  // fully coalesced
}

// Fused weight prep -> bf16 MFMA-fragment-linear order.
//  [0,64)    W0f  = bf16(fc0_w)           frag order
//  [64,192)  WC0f/WC1f = bf16(Ww @ conv_w[i]) frag order
//  [192,216) Wff  = bf16(out_w @ fc_out_w) padded to 48 rows, frag order; bfv fp32[48]
extern "C" __global__ void k_wprep(const float* __restrict__ fc0_w,
                                   const float* __restrict__ Ww, const float* __restrict__ cw,
                                   const float* __restrict__ ow, const float* __restrict__ fw,
                                   const float* __restrict__ fb, const float* __restrict__ ob,
                                   unsigned short* __restrict__ W0f, unsigned short* __restrict__ WC0f,
                                   unsigned short* __restrict__ WC1f, unsigned short* __restrict__ Wff,
                                   float* __restrict__ bfv){
  int b = blockIdx.x;
  if (b < 64){
    int idx = b*256 + threadIdx.x;
    int f = idx >> 7, k = idx & 127;
    W0f[fragidx(f, k)] = f2bf(fc0_w[f*128 + k]);
  } else if (b < 192){
    int idx = (b & 63)*256 + threadIdx.x;
    int f = idx >> 7, k = idx & 127;
    const float* c = (b < 128) ? cw : (cw + 16384);
    float acc = 0.f;
    #pragma unroll 4
    for (int j = 0; j < 128; ++j) acc = fmaf(Ww[f*128 + j], c[j*128 + k], acc);
    unsigned short* o = (b < 128) ? WC0f : WC1f;
    o[fragidx(f, k)] = f2bf(acc);
  } else {
    int idx = (b - 192)*256 + threadIdx.x;   // 0..6143 over 48x128
    int c = idx >> 7, k = idx & 127;
    float acc = 0.f;
    if (c < 40){
      for (int j = 0; j < 128; ++j) acc = fmaf(ow[c*128 + j], fw[j*128 + k], acc);
    }
    Wff[fragidx(c, k)] = f2bf(acc);
    if (idx < 48){
      float a2 = 0.f;
      if (idx < 40){
        a2 = ob[idx];
        for (int j = 0; j < 128; ++j) a2 = fmaf(ow[idx*128 + j], fb[j], a2);
      }
      bfv[idx] = a2;
    }
  }
}

// Agg[n] = dis[n] * sum_e dis[s_e] * Hf[s_e]
// One wave per node; 4 groups x 16 lanes (uint4 = full 256B row per group); unroll x2.
extern "C" __global__ __launch_bounds__(256)
void k_gather(const unsigned short* __restrict__ Hf, const unsigned short* __restrict__ csr,
              const float* __restrict__ dis, const int* __restrict__ offs,
              unsigned short* __restrict__ Agg){
  int lane = threadIdx.x & 63;
  int node = blockIdx.x*4 + (threadIdx.x >> 6);
  int grp  = lane >> 4;          // 0..3
  int q8   = (lane & 15)*8;      // 8 bf16 features per lane
  int start = offs[node];
  int n = offs[node+1] - start;  // >= 1 (self-loop)
  float dn = dis[node];
  float a0=0,a1=0,a2=0,a3=0,a4=0,a5=0,a6=0,a7=0;
  int nm1 = n - 1;
  for (int i = 0; i < n; i += 8){
    int k0 = i + grp;
    int k1 = i + 4 + grp;
    int c0 = (k0 < n) ? k0 : nm1;
    int c1 = (k1 < n) ? k1 : nm1;
    int s0 = csr[start + c0];
    int s1 = csr[start + c1];
    float w0 = (k0 < n) ? dis[s0] : 0.f;
    float w1 = (k1 < n) ? dis[s1] : 0.f;
    uint4 u0 = *reinterpret_cast<const uint4*>(Hf + s0*128 + q8);
    uint4 u1 = *reinterpret_cast<const uint4*>(Hf + s1*128 + q8);
    a0 = fmaf(lo2f(u0.x), w0, a0); a1 = fmaf(hi2f(u0.x), w0, a1);
    a2 = fmaf(lo2f(u0.y), w0, a2); a3 = fmaf(hi2f(u0.y), w0, a3);
    a4 = fmaf(lo2f(u0.z), w0, a4); a5 = fmaf(hi2f(u0.z), w0, a5);
    a6 = fmaf(lo2f(u0.w), w0, a6); a7 = fmaf(hi2f(u0.w), w0, a7);
    a0 = fmaf(lo2f(u1.x), w1, a0); a1 = fmaf(hi2f(u1.x), w1, a1);
    a2 = fmaf(lo2f(u1.y), w1, a2); a3 = fmaf(hi2f(u1.y), w1, a3);
    a4 = fmaf(lo2f(u1.z), w1, a4); a5 = fmaf(hi2f(u1.z), w1, a5);
    a6 = fmaf(lo2f(u1.w), w1, a6); a7 = fmaf(hi2f(u1.w), w1, a7);
  }
  a0 += __shfl_xor(a0, 16); a1 += __shfl_xor(a1, 16);
  a2 += __shfl_xor(a2, 16); a3 += __shfl_xor(a3, 16);
  a4 += __shfl_xor(a4, 16); a5 += __shfl_xor(a5, 16);
  a6 += __shfl_xor(a6, 16); a7 += __shfl_xor(a7, 16);
  a0 += __shfl_xor(a0, 32); a1 += __shfl_xor(a1, 32);
  a2 += __shfl_xor(a2, 32); a3 += __shfl_xor(a3, 32);
  a4 += __shfl_xor(a4, 32); a5 += __shfl_xor(a5, 32);
  a6 += __shfl_xor(a6, 32); a7 += __shfl_xor(a7, 32);
  if (grp == 0){
    uint4 o;
    o.x = pk2(a0*dn, a1*dn);
    o.y = pk2(a2*dn, a3*dn);
    o.z = pk2(a4*dn, a5*dn);
    o.w = pk2(a6*dn, a7*dn);
    *reinterpret_cast<uint4*>(Agg + node*128 + q8) = o;
  }
}

// MFMA GEMM: C = relu(bn((X @ W^T) + bias)) -> bf16 Cout; Jk(bf16): MODE1 =C, MODE2 max.
// 256 thr = 4 waves x 16 rows (BM=64); W staged frag-linear in LDS (conflict-free).
template<int MODE>
__global__ __launch_bounds__(256)
void k_mm(const float* __restrict__ Xf, const unsigned short* __restrict__ Xb,
          const unsigned short* __restrict__ Wf, const float* __restrict__ bias,
          const float* __restrict__ gamma, const float* __restrict__ beta,
          unsigned short* __restrict__ Cout, unsigned short* __restrict__ Jk){
  __shared__ uint4 Ws4[2048];                       // 32KB frag-linear weights
  unsigned short* Ws = (unsigned short*)Ws4;
  const int t = threadIdx.x;
  {
    const uint4* src = reinterpret_cast<const uint4*>(Wf);
    #pragma unroll
    for (int i = 0; i < 8; ++i) Ws4[i*256 + t] = src[i*256 + t];
  }
  const int lane = t & 63;
  const int wv = t >> 6;
  const int m0 = blockIdx.x*64 + wv*16;
  const int mrow = min(m0 + (lane & 15), NN-1);
  const int kg = (lane >> 4)*8;
  bf16x8 a[4];
  if constexpr (MODE == 1){
    const float* px = Xf + (size_t)mrow*128 + kg;
    #pragma unroll
    for (int ks = 0; ks < 4; ++ks){
      float4 f0 = ld4(px + ks*32);
      float4 f1 = ld4(px + ks*32 + 4);
      bf16x8 aa;
      aa[0]=(__bf16)f0.x; aa[1]=(__bf16)f0.y; aa[2]=(__bf16)f0.z; aa[3]=(__bf16)f0.w;
      aa[4]=(__bf16)f1.x; aa[5]=(__bf16)f1.y; aa[6]=(__bf16)f1.z; aa[7]=(__bf16)f1.w;
      a[ks] = aa;
    }
  } else {
    const unsigned short* px = Xb + (size_t)mrow*128 + kg;
    #pragma unroll
    for (int ks = 0; ks < 4; ++ks)
      a[ks] = *reinterpret_cast<const bf16x8*>(px + ks*32);
  }
  __syncthreads();
  f32x4 acc[8];
  #pragma unroll
  for (int nt = 0; nt < 8; ++nt) acc[nt] = (f32x4){0.f,0.f,0.f,0.f};
  #pragma unroll
  for (int ks = 0; ks < 4; ++ks){
    #pragma unroll
    for (int nt = 0; nt < 8; ++nt){
      bf16x8 bfr = *reinterpret_cast<const bf16x8*>(Ws + ((nt*4 + ks)*64 + lane)*8);
      acc[nt] = __builtin_amdgcn_mfma_f32_16x16x32_bf16(a[ks], bfr, acc[nt], 0, 0, 0);
    }
  }
  // epilogue: row = m0 + (lane>>4)*4 + r, col = nt*16 + (lane&15)
  const int cB = lane & 15;
  const int r0 = (lane >> 4)*4;
  #pragma unroll
  for (int nt = 0; nt < 8; ++nt){
    int cb = nt*16 + cB;
    float bi = bias[cb];
    float g  = gamma[cb]*BN_SC;
    float be = beta[cb];
    #pragma unroll
    for (int r = 0; r < 4; ++r){
      int row = m0 + r0 + r;
      if (row < NN){
        float o = fmaxf(fmaf(acc[nt][r] + bi, g, be), 0.f);
        unsigned short ub = f2bf(o);
        size_t ad = (size_t)row*128 + cb;
        Cout[ad] = ub;
        if (MODE == 1){
          Jk[ad] = ub;
        } else {
          unsigned short jo = Jk[ad];          // relu outputs >=0: u16 compare == float max
          Jk[ad] = (ub > jo) ? ub : jo;
        }
      }
    }
  }
}

// Final MFMA GEMM: Out[m][c] = Jk[m] . Wf[c] + bf[c], C=40 (padded 48). B frags in regs.
__global__ __launch_bounds__(256)
void k_final(const unsigned short* __restrict__ Jk, const unsigned short* __restrict__ Wff,
             const float* __restrict__ bfv, float* __restrict__ Out){
  const int t = threadIdx.x;
  const int lane = t & 63;
  const int wv = t >> 6;
  const int m0 = blockIdx.x*64 + wv*16;
  const int mrow = min(m0 + (lane & 15), NN-1);
  const int kg = (lane >> 4)*8;
  bf16x8 a[4];
  const unsigned short* px = Jk + (size_t)mrow*128 + kg;
  #pragma unroll
  for (int ks = 0; ks < 4; ++ks)
    a[ks] = *reinterpret_cast<const bf16x8*>(px + ks*32);
  bf16x8 b[3][4];
  #pragma unroll
  for (int nt = 0; nt < 3; ++nt)
    #pragma unroll
    for (int ks = 0; ks < 4; ++ks)
      b[nt][ks] = *reinterpret_cast<const bf16x8*>(Wff + ((nt*4 + ks)*64 + lane)*8);
  f32x4 acc[3];
  #pragma unroll
  for (int nt = 0; nt < 3; ++nt) acc[nt] = (f32x4){0.f,0.f,0.f,0.f};
  #pragma unroll
  for (int ks = 0; ks < 4; ++ks)
    #pragma unroll
    for (int nt = 0; nt < 3; ++nt)
      acc[nt] = __builtin_amdgcn_mfma_f32_16x16x32_bf16(a[ks], b[nt][ks], acc[nt], 0, 0, 0);
  const int cB = lane & 15;
  const int r0 = (lane >> 4)*4;
  #pragma unroll
  for (int nt = 0; nt < 3; ++nt){
    int cb = nt*16 + cB;
    if (cb < 40){
      float bi = bfv[cb];
      #pragma unroll
      for (int r = 0; r < 4; ++r){
        int row = m0 + r0 + r;
        if (row < NN) Out[(size_t)row*40 + cb] = acc[nt][r] + bi;
      }
    }
  }
}

extern "C" void kernel_launch(void* const* d_in, const int* in_sizes, int n_in,
                              void* d_out, int out_size, void* d_ws, size_t ws_size,
                              hipStream_t stream){
  const float* x     = (const float*)d_in[0];
  const int*   ei    = (const int*)d_in[1];
  const float* fc0_w = (const float*)d_in[2];
  const float* fc0_b = (const float*)d_in[3];
  const float* convw = (const float*)d_in[4];
  const float* Ww    = (const float*)d_in[5];
  const float* Wb    = (const float*)d_in[6];
  const float* bng   = (const float*)d_in[7];
  const float* bnb   = (const float*)d_in[8];
  const float* fow   = (const float*)d_in[9];
  const float* fob   = (const float*)d_in[10];
  const float* outw  = (const float*)d_in[11];
  const float* outb  = (const float*)d_in[12];
  float* out = (float*)d_out;

  char* p = (char*)d_ws;
  auto alloc = [&](size_t n){ char* r = p; p += (n + 255) & ~(size_t)255; return r; };
  int*   gbucket = (int*)  alloc((size_t)NB*4);
  int*   ebase   = (int*)  alloc((size_t)(NB+1)*4);
  int*   tbase   = (int*)  alloc((size_t)(NB+1)*4);
  int*   gcur    = (int*)  alloc((size_t)NB*4);
  unsigned int*   bbuf  = (unsigned int*)  alloc((size_t)NE*4);
  unsigned short* csr16 = (unsigned short*)alloc((size_t)EN*2);
  int*   offs    = (int*)  alloc((size_t)(NN+1)*4);
  float* dis     = (float*)alloc((size_t)NN*4);
  unsigned short* W0f  = (unsigned short*)alloc(16384*2);
  unsigned short* WC0f = (unsigned short*)alloc(16384*2);
  unsigned short* WC1f = (unsigned short*)alloc(16384*2);
  unsigned short* Wff  = (unsigned short*)alloc(6144*2);
  float* bfv     = (float*)alloc(64*4);
  unsigned short* H1  = (unsigned short*)alloc((size_t)NN*128*2);
  unsigned short* AGG = (unsigned short*)alloc((size_t)NN*128*2);
  unsigned short* JKb = (unsigned short*)alloc((size_t)NN*128*2);

  hipMemsetAsync(gbucket, 0, (size_t)NB*4, stream);
  k_bhist<<<BINBLK, 256, 0, stream>>>(ei, gbucket);
  k_bscan<<<1, 64, 0, stream>>>(gbucket, ebase, tbase, gcur);
  k_bin<<<BINBLK, 256, 0, stream>>>(ei, gcur, bbuf);
  k_csr<<<NB, 256, 0, stream>>>(bbuf, ebase, tbase, csr16, offs, dis);
  k_wprep<<<216, 256, 0, stream>>>(fc0_w, Ww, convw, outw, fow, fob, outb,
                                   W0f, WC0f, WC1f, Wff, bfv);

  k_mm<1><<<782, 256, 0, stream>>>(x, nullptr, W0f, fc0_b, bng, bnb, H1, JKb);
  k_gather<<<12500, 256, 0, stream>>>(H1, csr16, dis, offs, AGG);
  k_mm<2><<<782, 256, 0, stream>>>(nullptr, AGG, WC0f, Wb, bng + 128, bnb + 128, H1, JKb);
  k_gather<<<12500, 256, 0, stream>>>(H1, csr16, dis, offs, AGG);
  k_mm<2><<<782, 256, 0, stream>>>(nullptr, AGG, WC1f, Wb, bng + 256, bnb + 256, H1, JKb);
  k_final<<<782, 256, 0, stream>>>(JKb, Wff, bfv, out);
}

// Round 7
// 182.581 us; speedup vs baseline: 2.2883x; 1.0794x over previous
//
#include <hip/hip_runtime.h>

#define NN 50000
#define NE 800000
#define EN 850000
#define NB 196       // dst buckets of 256 nodes
#define BINBLK 391   // ceil(NE/2048)

static constexpr float BN_SC = 0.99999500003749968f; // 1/sqrt(1+1e-5)

typedef __bf16 bf16x8 __attribute__((ext_vector_type(8)));
typedef float  f32x4  __attribute__((ext_vector_type(4)));

__device__ __forceinline__ float4 ld4(const float* p){ return *reinterpret_cast<const float4*>(p); }

__device__ __forceinline__ float bf2f(unsigned short u){
  union { unsigned int i; float f; } v; v.i = ((unsigned int)u) << 16; return v.f;
}
__device__ __forceinline__ unsigned short f2bf(float f){
  union { float f; unsigned int i; } v; v.f = f;
  unsigned int r = v.i + 0x7fffu + ((v.i >> 16) & 1u);   // RNE
  return (unsigned short)(r >> 16);
}
__device__ __forceinline__ float lo2f(unsigned int u){
  union { unsigned int i; float f; } v; v.i = u << 16; return v.f;
}
__device__ __forceinline__ float hi2f(unsigned int u){
  union { unsigned int i; float f; } v; v.i = u & 0xffff0000u; return v.f;
}
__device__ __forceinline__ unsigned int pk2(float flo, float fhi){
  return (unsigned int)f2bf(flo) | ((unsigned int)f2bf(fhi) << 16);
}
// frag-linear index for B-operand element (n, k) of a 128-wide K matrix
__device__ __forceinline__ int fragidx(int n, int k){
  int nt = n >> 4, c = n & 15, ks = k >> 5, g = (k >> 3) & 3, j = k & 7;
  return ((nt*4 + ks)*64 + g*16 + c)*8 + j;
}

// ---- Level-0: per-bucket edge histogram (LDS-privatized) ----
extern "C" __global__ __launch_bounds__(256)
void k_bhist(const int* __restrict__ ei, int* __restrict__ gbucket){
  __shared__ int h[NB];
  int t = threadIdx.x;
  if (t < NB) h[t] = 0;
  __syncthreads();
  int e0 = blockIdx.x*2048;
  for (int i = t; i < 2048; i += 256){
    int e = e0 + i;
    if (e < NE) atomicAdd(&h[ei[NE+e] >> 8], 1);
  }
  __syncthreads();
  if (t < NB && h[t] > 0) atomicAdd(&gbucket[t], h[t]);
}

// ---- bucket base offsets (edge-only and with analytic self-loops) ----
extern "C" __global__ void k_bscan(const int* __restrict__ gbucket, int* __restrict__ ebase,
                                   int* __restrict__ tbase, int* __restrict__ gcur){
  if (threadIdx.x == 0){
    int runE = 0, runT = 0;
    for (int b = 0; b < NB; ++b){
      int ge = gbucket[b];
      int sc = (b < NB-1) ? 256 : (NN - (NB-1)*256);
      ebase[b] = runE; gcur[b] = runE; tbase[b] = runT;
      runE += ge; runT += ge + sc;
    }
    ebase[NB] = runE; tbase[NB] = runT;
  }
}

// ---- Level-1: bin edges by bucket; LDS-staged, run-coalesced flush ----
extern "C" __global__ __launch_bounds__(256)
void k_bin(const int* __restrict__ ei, int* __restrict__ gcur, unsigned int* __restrict__ bbuf){
  __shared__ int h[NB], lbase[NB], gbase[NB];
  __shared__ int tot;
  __shared__ unsigned int stage[2048];
  __shared__ unsigned char bid[2048];
  int t = threadIdx.x;
  if (t < NB) h[t] = 0;
  __syncthreads();
  int e0 = blockIdx.x*2048;
  for (int i = t; i < 2048; i += 256){
    int e = e0 + i;
    if (e < NE) atomicAdd(&h[ei[NE+e] >> 8], 1);
  }
  __syncthreads();
  if (t == 0){
    int run = 0;
    for (int b = 0; b < NB; ++b){ lbase[b] = run; run += h[b]; }
    tot = run;
  }
  __syncthreads();
  if (t < NB && h[t] > 0) gbase[t] = atomicAdd(&gcur[t], h[t]);  // one atomic per (block,bucket)
  __syncthreads();
  if (t < NB) h[t] = lbase[t];      // reuse as LDS placement cursor
  __syncthreads();
  for (int i = t; i < 2048; i += 256){
    int e = e0 + i;
    if (e < NE){
      int s = ei[e], d = ei[NE+e];
      int b = d >> 8;
      int p = atomicAdd(&h[b], 1);
      stage[p] = ((unsigned int)d << 16) | (unsigned int)s;   // node ids < 2^16
      bid[p] = (unsigned char)b;
    }
  }
  __syncthreads();
  int m = tot;
  for (int j = t; j < m; j += 256){
    int b = bid[j];
    bbuf[gbase[b] + (j - lbase[b])] = stage[j];               // contiguous per-bucket runs
  }
}

// ---- Level-2: per-bucket counting sort -> final CSR (u16 src), offs, dis ----
extern "C" __global__ __launch_bounds__(256)
void k_csr(const unsigned int* __restrict__ bbuf, const int* __restrict__ ebase,
           const int* __restrict__ tbase, unsigned short* __restrict__ csr,
           int* __restrict__ offs, float* __restrict__ dis){
  __shared__ int h[256], loff[256], lcur[256];
  __shared__ unsigned short stage[8192];
  int t = threadIdx.x;
  int b = blockIdx.x;
  int nb0 = b << 8;
  int BNv = min(256, NN - nb0);
  int ebeg = ebase[b];
  int m = ebase[b+1] - ebeg;
  int base = tbase[b];
  h[t] = (t < BNv) ? 1 : 0;    // self-loop
  __syncthreads();
  for (int i = t; i < m; i += 256)
    atomicAdd(&h[(bbuf[ebeg + i] >> 16) & 255], 1);
  __syncthreads();
  if (t == 0){
    int run = 0;
    for (int n = 0; n < BNv; ++n){ loff[n] = run; run += h[n]; }
  }
  __syncthreads();
  if (t < BNv){
    offs[nb0 + t] = base + loff[t];
    dis[nb0 + t] = rsqrtf((float)h[t]);
    lcur[t] = loff[t] + 1;
    stage[loff[t]] = (unsigned short)(nb0 + t);   // self-loop edge first
  }
  if (b == NB-1 && t == 0) offs[NN] = EN;
  __syncthreads();
  for (int i = t; i < m; i += 256){
    unsigned int e = bbuf[ebeg + i];
    int p = atomicAdd(&lcur[(e >> 16) & 255], 1);
    stage[p] = (unsigned short)(e & 0xffffu);
  }
  __syncthreads();
  int M = m + BNv;
  for (int j = t; j < M; j += 256) csr[base + j] = stage[j];  // fully coalesced
}

// Fused weight prep -> bf16 MFMA-fragment-linear order. Launched FIRST; block 215
// additionally zeroes gbucket (replaces the hipMemsetAsync graph node).
extern "C" __global__ void k_wprep(const float* __restrict__ fc0_w,
                                   const float* __restrict__ Ww, const float* __restrict__ cw,
                                   const float* __restrict__ ow, const float* __restrict__ fw,
                                   const float* __restrict__ fb, const float* __restrict__ ob,
                                   unsigned short* __restrict__ W0f, unsigned short* __restrict__ WC0f,
                                   unsigned short* __restrict__ WC1f, unsigned short* __restrict__ Wff,
                                   float* __restrict__ bfv, int* __restrict__ gbucket){
  int b = blockIdx.x;
  if (b < 64){
    int idx = b*256 + threadIdx.x;
    int f = idx >> 7, k = idx & 127;
    W0f[fragidx(f, k)] = f2bf(fc0_w[f*128 + k]);
  } else if (b < 192){
    int idx = (b & 63)*256 + threadIdx.x;
    int f = idx >> 7, k = idx & 127;
    const float* c = (b < 128) ? cw : (cw + 16384);
    float acc = 0.f;
    #pragma unroll 4
    for (int j = 0; j < 128; ++j) acc = fmaf(Ww[f*128 + j], c[j*128 + k], acc);
    unsigned short* o = (b < 128) ? WC0f : WC1f;
    o[fragidx(f, k)] = f2bf(acc);
  } else {
    int idx = (b - 192)*256 + threadIdx.x;   // 0..6143 over 48x128
    int c = idx >> 7, k = idx & 127;
    float acc = 0.f;
    if (c < 40){
      for (int j = 0; j < 128; ++j) acc = fmaf(ow[c*128 + j], fw[j*128 + k], acc);
    }
    Wff[fragidx(c, k)] = f2bf(acc);
    if (idx < 48){
      float a2 = 0.f;
      if (idx < 40){
        a2 = ob[idx];
        for (int j = 0; j < 128; ++j) a2 = fmaf(ow[idx*128 + j], fb[j], a2);
      }
      bfv[idx] = a2;
    }
    if (b == 215 && threadIdx.x < NB) gbucket[threadIdx.x] = 0;
  }
}

// Agg[n] = dis[n] * sum_e dis[s_e] * Hf[s_e]
// One wave per node; 4 groups x 16 lanes (uint4 = full 256B row per group); unroll x4
// -> 16 independent row loads in flight. Tail via clamp + zero weight (no divergence).
extern "C" __global__ __launch_bounds__(256)
void k_gather(const unsigned short* __restrict__ Hf, const unsigned short* __restrict__ csr,
              const float* __restrict__ dis, const int* __restrict__ offs,
              unsigned short* __restrict__ Agg){
  int lane = threadIdx.x & 63;
  int node = blockIdx.x*4 + (threadIdx.x >> 6);
  int grp  = lane >> 4;          // 0..3
  int q8   = (lane & 15)*8;      // 8 bf16 features per lane
  int start = offs[node];
  int n = offs[node+1] - start;  // >= 1 (self-loop)
  float dn = dis[node];
  float a0=0,a1=0,a2=0,a3=0,a4=0,a5=0,a6=0,a7=0;
  int nm1 = n - 1;
  for (int i = 0; i < n; i += 16){
    int k0 = i + grp, k1 = i + 4 + grp, k2 = i + 8 + grp, k3 = i + 12 + grp;
    int c0 = min(k0, nm1), c1 = min(k1, nm1), c2 = min(k2, nm1), c3 = min(k3, nm1);
    int s0 = csr[start + c0];
    int s1 = csr[start + c1];
    int s2 = csr[start + c2];
    int s3 = csr[start + c3];
    float w0 = (k0 < n) ? dis[s0] : 0.f;
    float w1 = (k1 < n) ? dis[s1] : 0.f;
    float w2 = (k2 < n) ? dis[s2] : 0.f;
    float w3 = (k3 < n) ? dis[s3] : 0.f;
    uint4 u0 = *reinterpret_cast<const uint4*>(Hf + s0*128 + q8);
    uint4 u1 = *reinterpret_cast<const uint4*>(Hf + s1*128 + q8);
    uint4 u2 = *reinterpret_cast<const uint4*>(Hf + s2*128 + q8);
    uint4 u3 = *reinterpret_cast<const uint4*>(Hf + s3*128 + q8);
    a0 = fmaf(lo2f(u0.x), w0, a0); a1 = fmaf(hi2f(u0.x), w0, a1);
    a2 = fmaf(lo2f(u0.y), w0, a2); a3 = fmaf(hi2f(u0.y), w0, a3);
    a4 = fmaf(lo2f(u0.z), w0, a4); a5 = fmaf(hi2f(u0.z), w0, a5);
    a6 = fmaf(lo2f(u0.w), w0, a6); a7 = fmaf(hi2f(u0.w), w0, a7);
    a0 = fmaf(lo2f(u1.x), w1, a0); a1 = fmaf(hi2f(u1.x), w1, a1);
    a2 = fmaf(lo2f(u1.y), w1, a2); a3 = fmaf(hi2f(u1.y), w1, a3);
    a4 = fmaf(lo2f(u1.z), w1, a4); a5 = fmaf(hi2f(u1.z), w1, a5);
    a6 = fmaf(lo2f(u1.w), w1, a6); a7 = fmaf(hi2f(u1.w), w1, a7);
    a0 = fmaf(lo2f(u2.x), w2, a0); a1 = fmaf(hi2f(u2.x), w2, a1);
    a2 = fmaf(lo2f(u2.y), w2, a2); a3 = fmaf(hi2f(u2.y), w2, a3);
    a4 = fmaf(lo2f(u2.z), w2, a4); a5 = fmaf(hi2f(u2.z), w2, a5);
    a6 = fmaf(lo2f(u2.w), w2, a6); a7 = fmaf(hi2f(u2.w), w2, a7);
    a0 = fmaf(lo2f(u3.x), w3, a0); a1 = fmaf(hi2f(u3.x), w3, a1);
    a2 = fmaf(lo2f(u3.y), w3, a2); a3 = fmaf(hi2f(u3.y), w3, a3);
    a4 = fmaf(lo2f(u3.z), w3, a4); a5 = fmaf(hi2f(u3.z), w3, a5);
    a6 = fmaf(lo2f(u3.w), w3, a6); a7 = fmaf(hi2f(u3.w), w3, a7);
  }
  a0 += __shfl_xor(a0, 16); a1 += __shfl_xor(a1, 16);
  a2 += __shfl_xor(a2, 16); a3 += __shfl_xor(a3, 16);
  a4 += __shfl_xor(a4, 16); a5 += __shfl_xor(a5, 16);
  a6 += __shfl_xor(a6, 16); a7 += __shfl_xor(a7, 16);
  a0 += __shfl_xor(a0, 32); a1 += __shfl_xor(a1, 32);
  a2 += __shfl_xor(a2, 32); a3 += __shfl_xor(a3, 32);
  a4 += __shfl_xor(a4, 32); a5 += __shfl_xor(a5, 32);
  a6 += __shfl_xor(a6, 32); a7 += __shfl_xor(a7, 32);
  if (grp == 0){
    uint4 o;
    o.x = pk2(a0*dn, a1*dn);
    o.y = pk2(a2*dn, a3*dn);
    o.z = pk2(a4*dn, a5*dn);
    o.w = pk2(a6*dn, a7*dn);
    *reinterpret_cast<uint4*>(Agg + node*128 + q8) = o;
  }
}

// MFMA GEMM: C = relu(bn((X @ W^T) + bias)) -> bf16 Cout; Jk(bf16): MODE1 =C, MODE2 max.
// 256 thr = 4 waves x 16 rows (BM=64); W staged frag-linear in LDS (conflict-free).
template<int MODE>
__global__ __launch_bounds__(256)
void k_mm(const float* __restrict__ Xf, const unsigned short* __restrict__ Xb,
          const unsigned short* __restrict__ Wf, const float* __restrict__ bias,
          const float* __restrict__ gamma, const float* __restrict__ beta,
          unsigned short* __restrict__ Cout, unsigned short* __restrict__ Jk){
  __shared__ uint4 Ws4[2048];                       // 32KB frag-linear weights
  unsigned short* Ws = (unsigned short*)Ws4;
  const int t = threadIdx.x;
  {
    const uint4* src = reinterpret_cast<const uint4*>(Wf);
    #pragma unroll
    for (int i = 0; i < 8; ++i) Ws4[i*256 + t] = src[i*256 + t];
  }
  const int lane = t & 63;
  const int wv = t >> 6;
  const int m0 = blockIdx.x*64 + wv*16;
  const int mrow = min(m0 + (lane & 15), NN-1);
  const int kg = (lane >> 4)*8;
  bf16x8 a[4];
  if constexpr (MODE == 1){
    const float* px = Xf + (size_t)mrow*128 + kg;
    #pragma unroll
    for (int ks = 0; ks < 4; ++ks){
      float4 f0 = ld4(px + ks*32);
      float4 f1 = ld4(px + ks*32 + 4);
      bf16x8 aa;
      aa[0]=(__bf16)f0.x; aa[1]=(__bf16)f0.y; aa[2]=(__bf16)f0.z; aa[3]=(__bf16)f0.w;
      aa[4]=(__bf16)f1.x; aa[5]=(__bf16)f1.y; aa[6]=(__bf16)f1.z; aa[7]=(__bf16)f1.w;
      a[ks] = aa;
    }
  } else {
    const unsigned short* px = Xb + (size_t)mrow*128 + kg;
    #pragma unroll
    for (int ks = 0; ks < 4; ++ks)
      a[ks] = *reinterpret_cast<const bf16x8*>(px + ks*32);
  }
  __syncthreads();
  f32x4 acc[8];
  #pragma unroll
  for (int nt = 0; nt < 8; ++nt) acc[nt] = (f32x4){0.f,0.f,0.f,0.f};
  #pragma unroll
  for (int ks = 0; ks < 4; ++ks){
    #pragma unroll
    for (int nt = 0; nt < 8; ++nt){
      bf16x8 bfr = *reinterpret_cast<const bf16x8*>(Ws + ((nt*4 + ks)*64 + lane)*8);
      acc[nt] = __builtin_amdgcn_mfma_f32_16x16x32_bf16(a[ks], bfr, acc[nt], 0, 0, 0);
    }
  }
  // epilogue: row = m0 + (lane>>4)*4 + r, col = nt*16 + (lane&15)
  const int cB = lane & 15;
  const int r0 = (lane >> 4)*4;
  #pragma unroll
  for (int nt = 0; nt < 8; ++nt){
    int cb = nt*16 + cB;
    float bi = bias[cb];
    float g  = gamma[cb]*BN_SC;
    float be = beta[cb];
    #pragma unroll
    for (int r = 0; r < 4; ++r){
      int row = m0 + r0 + r;
      if (row < NN){
        float o = fmaxf(fmaf(acc[nt][r] + bi, g, be), 0.f);
        unsigned short ub = f2bf(o);
        size_t ad = (size_t)row*128 + cb;
        Cout[ad] = ub;
        if (MODE == 1){
          Jk[ad] = ub;
        } else {
          unsigned short jo = Jk[ad];          // relu outputs >=0: u16 compare == float max
          Jk[ad] = (ub > jo) ? ub : jo;
        }
      }
    }
  }
}

// Final MFMA GEMM: Out[m][c] = Jk[m] . Wf[c] + bf[c], C=40 (padded 48). B frags in regs.
__global__ __launch_bounds__(256)
void k_final(const unsigned short* __restrict__ Jk, const unsigned short* __restrict__ Wff,
             const float* __restrict__ bfv, float* __restrict__ Out){
  const int t = threadIdx.x;
  const int lane = t & 63;
  const int wv = t >> 6;
  const int m0 = blockIdx.x*64 + wv*16;
  const int mrow = min(m0 + (lane & 15), NN-1);
  const int kg = (lane >> 4)*8;
  bf16x8 a[4];
  const unsigned short* px = Jk + (size_t)mrow*128 + kg;
  #pragma unroll
  for (int ks = 0; ks < 4; ++ks)
    a[ks] = *reinterpret_cast<const bf16x8*>(px + ks*32);
  bf16x8 b[3][4];
  #pragma unroll
  for (int nt = 0; nt < 3; ++nt)
    #pragma unroll
    for (int ks = 0; ks < 4; ++ks)
      b[nt][ks] = *reinterpret_cast<const bf16x8*>(Wff + ((nt*4 + ks)*64 + lane)*8);
  f32x4 acc[3];
  #pragma unroll
  for (int nt = 0; nt < 3; ++nt) acc[nt] = (f32x4){0.f,0.f,0.f,0.f};
  #pragma unroll
  for (int ks = 0; ks < 4; ++ks)
    #pragma unroll
    for (int nt = 0; nt < 3; ++nt)
      acc[nt] = __builtin_amdgcn_mfma_f32_16x16x32_bf16(a[ks], b[nt][ks], acc[nt], 0, 0, 0);
  const int cB = lane & 15;
  const int r0 = (lane >> 4)*4;
  #pragma unroll
  for (int nt = 0; nt < 3; ++nt){
    int cb = nt*16 + cB;
    if (cb < 40){
      float bi = bfv[cb];
      #pragma unroll
      for (int r = 0; r < 4; ++r){
        int row = m0 + r0 + r;
        if (row < NN) Out[(size_t)row*40 + cb] = acc[nt][r] + bi;
      }
    }
  }
}

extern "C" void kernel_launch(void* const* d_in, const int* in_sizes, int n_in,
                              void* d_out, int out_size, void* d_ws, size_t ws_size,
                              hipStream_t stream){
  const float* x     = (const float*)d_in[0];
  const int*   ei    = (const int*)d_in[1];
  const float* fc0_w = (const float*)d_in[2];
  const float* fc0_b = (const float*)d_in[3];
  const float* convw = (const float*)d_in[4];
  const float* Ww    = (const float*)d_in[5];
  const float* Wb    = (const float*)d_in[6];
  const float* bng   = (const float*)d_in[7];
  const float* bnb   = (const float*)d_in[8];
  const float* fow   = (const float*)d_in[9];
  const float* fob   = (const float*)d_in[10];
  const float* outw  = (const float*)d_in[11];
  const float* outb  = (const float*)d_in[12];
  float* out = (float*)d_out;

  char* p = (char*)d_ws;
  auto alloc = [&](size_t n){ char* r = p; p += (n + 255) & ~(size_t)255; return r; };
  int*   gbucket = (int*)  alloc((size_t)NB*4);
  int*   ebase   = (int*)  alloc((size_t)(NB+1)*4);
  int*   tbase   = (int*)  alloc((size_t)(NB+1)*4);
  int*   gcur    = (int*)  alloc((size_t)NB*4);
  unsigned int*   bbuf  = (unsigned int*)  alloc((size_t)NE*4);
  unsigned short* csr16 = (unsigned short*)alloc((size_t)EN*2);
  int*   offs    = (int*)  alloc((size_t)(NN+1)*4);
  float* dis     = (float*)alloc((size_t)NN*4);
  unsigned short* W0f  = (unsigned short*)alloc(16384*2);
  unsigned short* WC0f = (unsigned short*)alloc(16384*2);
  unsigned short* WC1f = (unsigned short*)alloc(16384*2);
  unsigned short* Wff  = (unsigned short*)alloc(6144*2);
  float* bfv     = (float*)alloc(64*4);
  unsigned short* H1  = (unsigned short*)alloc((size_t)NN*128*2);
  unsigned short* AGG = (unsigned short*)alloc((size_t)NN*128*2);
  unsigned short* JKb = (unsigned short*)alloc((size_t)NN*128*2);

  k_wprep<<<216, 256, 0, stream>>>(fc0_w, Ww, convw, outw, fow, fob, outb,
                                   W0f, WC0f, WC1f, Wff, bfv, gbucket);
  k_bhist<<<BINBLK, 256, 0, stream>>>(ei, gbucket);
  k_bscan<<<1, 64, 0, stream>>>(gbucket, ebase, tbase, gcur);
  k_bin<<<BINBLK, 256, 0, stream>>>(ei, gcur, bbuf);
  k_csr<<<NB, 256, 0, stream>>>(bbuf, ebase, tbase, csr16, offs, dis);

  k_mm<1><<<782, 256, 0, stream>>>(x, nullptr, W0f, fc0_b, bng, bnb, H1, JKb);
  k_gather<<<12500, 256, 0, stream>>>(H1, csr16, dis, offs, AGG);
  k_mm<2><<<782, 256, 0, stream>>>(nullptr, AGG, WC0f, Wb, bng + 128, bnb + 128, H1, JKb);
  k_gather<<<12500, 256, 0, stream>>>(H1, csr16, dis, offs, AGG);
  k_mm<2><<<782, 256, 0, stream>>>(nullptr, AGG, WC1f, Wb, bng + 256, bnb + 256, H1, JKb);
  k_final<<<782, 256, 0, stream>>>(JKb, Wff, bfv, out);
}

// Round 8
// 168.559 us; speedup vs baseline: 2.4787x; 1.0832x over previous
//
#include <hip/hip_runtime.h>

#define NN 50000
#define NE 800000
#define EN 850000
#define NB 196       // dst buckets of 256 nodes
#define BINBLK 391   // ceil(NE/2048)

static constexpr float BN_SC = 0.99999500003749968f; // 1/sqrt(1+1e-5)

typedef __bf16 bf16x8 __attribute__((ext_vector_type(8)));
typedef float  f32x4  __attribute__((ext_vector_type(4)));

__device__ __forceinline__ float4 ld4(const float* p){ return *reinterpret_cast<const float4*>(p); }

__device__ __forceinline__ unsigned short f2bf(float f){
  union { float f; unsigned int i; } v; v.f = f;
  unsigned int r = v.i + 0x7fffu + ((v.i >> 16) & 1u);   // RNE
  return (unsigned short)(r >> 16);
}
__device__ __forceinline__ float lo2f(unsigned int u){
  union { unsigned int i; float f; } v; v.i = u << 16; return v.f;
}
__device__ __forceinline__ float hi2f(unsigned int u){
  union { unsigned int i; float f; } v; v.i = u & 0xffff0000u; return v.f;
}
__device__ __forceinline__ unsigned int pk2(float flo, float fhi){
  return (unsigned int)f2bf(flo) | ((unsigned int)f2bf(fhi) << 16);
}
// frag-linear index for B-operand element (n, k) of a 128-wide K matrix
__device__ __forceinline__ int fragidx(int n, int k){
  int nt = n >> 4, c = n & 15, ks = k >> 5, g = (k >> 3) & 3, j = k & 7;
  return ((nt*4 + ks)*64 + g*16 + c)*8 + j;
}

// ---- K1: fused weight prep + per-block edge histograms ----
//  [0,64)    W0f  = bf16(fc0_w) frag order
//  [64,192)  WC0f/WC1f = bf16(Ww @ conv_w[i]) frag order
//  [192,216) Wff  = bf16(out_w @ fc_out_w) padded to 48 rows; bfv fp32[48]
//  [216,607) bhist: hists[bb][NB] per-block dst-bucket histogram (no atomics, no init needed)
extern "C" __global__ __launch_bounds__(256)
void k_prep(const float* __restrict__ fc0_w,
            const float* __restrict__ Ww, const float* __restrict__ cw,
            const float* __restrict__ ow, const float* __restrict__ fw,
            const float* __restrict__ fb, const float* __restrict__ ob,
            const int* __restrict__ ei,
            unsigned short* __restrict__ W0f, unsigned short* __restrict__ WC0f,
            unsigned short* __restrict__ WC1f, unsigned short* __restrict__ Wff,
            float* __restrict__ bfv, int* __restrict__ hists){
  int b = blockIdx.x;
  int t = threadIdx.x;
  if (b < 64){
    int idx = b*256 + t;
    int f = idx >> 7, k = idx & 127;
    W0f[fragidx(f, k)] = f2bf(fc0_w[f*128 + k]);
  } else if (b < 192){
    int idx = (b & 63)*256 + t;
    int f = idx >> 7, k = idx & 127;
    const float* c = (b < 128) ? cw : (cw + 16384);
    float acc = 0.f;
    #pragma unroll 4
    for (int j = 0; j < 128; ++j) acc = fmaf(Ww[f*128 + j], c[j*128 + k], acc);
    unsigned short* o = (b < 128) ? WC0f : WC1f;
    o[fragidx(f, k)] = f2bf(acc);
  } else if (b < 216){
    int idx = (b - 192)*256 + t;   // 0..6143 over 48x128
    int c = idx >> 7, k = idx & 127;
    float acc = 0.f;
    if (c < 40){
      for (int j = 0; j < 128; ++j) acc = fmaf(ow[c*128 + j], fw[j*128 + k], acc);
    }
    Wff[fragidx(c, k)] = f2bf(acc);
    if (idx < 48){
      float a2 = 0.f;
      if (idx < 40){
        a2 = ob[idx];
        for (int j = 0; j < 128; ++j) a2 = fmaf(ow[idx*128 + j], fb[j], a2);
      }
      bfv[idx] = a2;
    }
  } else {
    __shared__ int h[NB];
    int bb = b - 216;
    if (t < NB) h[t] = 0;
    __syncthreads();
    int e0 = bb*2048;
    for (int i = t; i < 2048; i += 256){
      int e = e0 + i;
      if (e < NE) atomicAdd(&h[ei[NE+e] >> 8], 1);
    }
    __syncthreads();
    if (t < NB) hists[bb*NB + t] = h[t];
  }
}

// ---- K2: bucket totals + exclusive scan -> ebase (tbase[b] == ebase[b]+256*b) ----
extern "C" __global__ __launch_bounds__(1024)
void k_bscan(const int* __restrict__ hists, int* __restrict__ ebase, int* __restrict__ gcur){
  __shared__ int part[1024];
  __shared__ int lds[256];
  int t = threadIdx.x;
  int bk = t & 255, chunk = t >> 8;           // 4 chunks of <=98 rows
  int i0 = chunk*98, i1 = min(i0 + 98, BINBLK);
  int sum = 0;
  if (bk < NB) for (int i = i0; i < i1; ++i) sum += hists[i*NB + bk];
  part[t] = sum;
  __syncthreads();
  int s = 0;
  if (t < 256) s = part[t] + part[t+256] + part[t+512] + part[t+768];
  if (t < 256) lds[t] = s;
  __syncthreads();
  int acc = s;
  #pragma unroll
  for (int off = 1; off < 256; off <<= 1){
    int x = (t >= off && t < 256) ? lds[t-off] : 0;
    __syncthreads();
    if (t < 256){ acc += x; lds[t] = acc; }
    __syncthreads();
  }
  if (t < NB){
    int excl = acc - s;
    ebase[t] = excl; gcur[t] = excl;
  }
  if (t == 0) ebase[NB] = NE;
}

// ---- K3: bin edges by bucket; LDS-staged, run-coalesced flush ----
extern "C" __global__ __launch_bounds__(256)
void k_bin(const int* __restrict__ ei, int* __restrict__ gcur, unsigned int* __restrict__ bbuf){
  __shared__ int h[NB], lbase[NB], gbase[NB];
  __shared__ int tot;
  __shared__ unsigned int stage[2048];
  __shared__ unsigned char bid[2048];
  int t = threadIdx.x;
  if (t < NB) h[t] = 0;
  __syncthreads();
  int e0 = blockIdx.x*2048;
  for (int i = t; i < 2048; i += 256){
    int e = e0 + i;
    if (e < NE) atomicAdd(&h[ei[NE+e] >> 8], 1);
  }
  __syncthreads();
  if (t == 0){
    int run = 0;
    for (int b = 0; b < NB; ++b){ lbase[b] = run; run += h[b]; }
    tot = run;
  }
  __syncthreads();
  if (t < NB && h[t] > 0) gbase[t] = atomicAdd(&gcur[t], h[t]);  // one atomic per (block,bucket)
  __syncthreads();
  if (t < NB) h[t] = lbase[t];      // reuse as LDS placement cursor
  __syncthreads();
  for (int i = t; i < 2048; i += 256){
    int e = e0 + i;
    if (e < NE){
      int s = ei[e], d = ei[NE+e];
      int b = d >> 8;
      int p = atomicAdd(&h[b], 1);
      stage[p] = ((unsigned int)d << 16) | (unsigned int)s;   // node ids < 2^16
      bid[p] = (unsigned char)b;
    }
  }
  __syncthreads();
  int m = tot;
  for (int j = t; j < m; j += 256){
    int b = bid[j];
    bbuf[gbase[b] + (j - lbase[b])] = stage[j];               // contiguous per-bucket runs
  }
}

// ---- K4: per-bucket counting sort -> final CSR (u16 src), offs, dis ----
extern "C" __global__ __launch_bounds__(256)
void k_csr(const unsigned int* __restrict__ bbuf, const int* __restrict__ ebase,
           unsigned short* __restrict__ csr, int* __restrict__ offs, float* __restrict__ dis){
  __shared__ int h[256], loff[256], lcur[256];
  __shared__ unsigned short stage[8192];
  int t = threadIdx.x;
  int b = blockIdx.x;
  int nb0 = b << 8;
  int BNv = min(256, NN - nb0);
  int ebeg = ebase[b];
  int m = ebase[b+1] - ebeg;
  int base = ebeg + (b << 8);          // tbase[b] = ebase[b] + 256*b
  h[t] = (t < BNv) ? 1 : 0;            // self-loop
  __syncthreads();
  for (int i = t; i < m; i += 256)
    atomicAdd(&h[(bbuf[ebeg + i] >> 16) & 255], 1);
  __syncthreads();
  if (t == 0){
    int run = 0;
    for (int n = 0; n < BNv; ++n){ loff[n] = run; run += h[n]; }
  }
  __syncthreads();
  if (t < BNv){
    offs[nb0 + t] = base + loff[t];
    dis[nb0 + t] = rsqrtf((float)h[t]);
    lcur[t] = loff[t] + 1;
    stage[loff[t]] = (unsigned short)(nb0 + t);   // self-loop edge first
  }
  if (b == NB-1 && t == 0) offs[NN] = EN;
  __syncthreads();
  for (int i = t; i < m; i += 256){
    unsigned int e = bbuf[ebeg + i];
    int p = atomicAdd(&lcur[(e >> 16) & 255], 1);
    stage[p] = (unsigned short)(e & 0xffffu);
  }
  __syncthreads();
  int M = m + BNv;
  for (int j = t; j < M; j += 256) csr[base + j] = stage[j];  // fully coalesced
}

// Agg[n] = dis[n] * sum_e dis[s_e] * Hf[s_e]
// One wave per node; 4 groups x 16 lanes (uint4 = full 256B row per group); unroll x4.
extern "C" __global__ __launch_bounds__(256)
void k_gather(const unsigned short* __restrict__ Hf, const unsigned short* __restrict__ csr,
              const float* __restrict__ dis, const int* __restrict__ offs,
              unsigned short* __restrict__ Agg){
  int lane = threadIdx.x & 63;
  int node = blockIdx.x*4 + (threadIdx.x >> 6);
  int grp  = lane >> 4;          // 0..3
  int q8   = (lane & 15)*8;      // 8 bf16 features per lane
  int start = offs[node];
  int n = offs[node+1] - start;  // >= 1 (self-loop)
  float dn = dis[node];
  float a0=0,a1=0,a2=0,a3=0,a4=0,a5=0,a6=0,a7=0;
  int nm1 = n - 1;
  for (int i = 0; i < n; i += 16){
    int k0 = i + grp, k1 = i + 4 + grp, k2 = i + 8 + grp, k3 = i + 12 + grp;
    int c0 = min(k0, nm1), c1 = min(k1, nm1), c2 = min(k2, nm1), c3 = min(k3, nm1);
    int s0 = csr[start + c0];
    int s1 = csr[start + c1];
    int s2 = csr[start + c2];
    int s3 = csr[start + c3];
    float w0 = (k0 < n) ? dis[s0] : 0.f;
    float w1 = (k1 < n) ? dis[s1] : 0.f;
    float w2 = (k2 < n) ? dis[s2] : 0.f;
    float w3 = (k3 < n) ? dis[s3] : 0.f;
    uint4 u0 = *reinterpret_cast<const uint4*>(Hf + s0*128 + q8);
    uint4 u1 = *reinterpret_cast<const uint4*>(Hf + s1*128 + q8);
    uint4 u2 = *reinterpret_cast<const uint4*>(Hf + s2*128 + q8);
    uint4 u3 = *reinterpret_cast<const uint4*>(Hf + s3*128 + q8);
    a0 = fmaf(lo2f(u0.x), w0, a0); a1 = fmaf(hi2f(u0.x), w0, a1);
    a2 = fmaf(lo2f(u0.y), w0, a2); a3 = fmaf(hi2f(u0.y), w0, a3);
    a4 = fmaf(lo2f(u0.z), w0, a4); a5 = fmaf(hi2f(u0.z), w0, a5);
    a6 = fmaf(lo2f(u0.w), w0, a6); a7 = fmaf(hi2f(u0.w), w0, a7);
    a0 = fmaf(lo2f(u1.x), w1, a0); a1 = fmaf(hi2f(u1.x), w1, a1);
    a2 = fmaf(lo2f(u1.y), w1, a2); a3 = fmaf(hi2f(u1.y), w1, a3);
    a4 = fmaf(lo2f(u1.z), w1, a4); a5 = fmaf(hi2f(u1.z), w1, a5);
    a6 = fmaf(lo2f(u1.w), w1, a6); a7 = fmaf(hi2f(u1.w), w1, a7);
    a0 = fmaf(lo2f(u2.x), w2, a0); a1 = fmaf(hi2f(u2.x), w2, a1);
    a2 = fmaf(lo2f(u2.y), w2, a2); a3 = fmaf(hi2f(u2.y), w2, a3);
    a4 = fmaf(lo2f(u2.z), w2, a4); a5 = fmaf(hi2f(u2.z), w2, a5);
    a6 = fmaf(lo2f(u2.w), w2, a6); a7 = fmaf(hi2f(u2.w), w2, a7);
    a0 = fmaf(lo2f(u3.x), w3, a0); a1 = fmaf(hi2f(u3.x), w3, a1);
    a2 = fmaf(lo2f(u3.y), w3, a2); a3 = fmaf(hi2f(u3.y), w3, a3);
    a4 = fmaf(lo2f(u3.z), w3, a4); a5 = fmaf(hi2f(u3.z), w3, a5);
    a6 = fmaf(lo2f(u3.w), w3, a6); a7 = fmaf(hi2f(u3.w), w3, a7);
  }
  a0 += __shfl_xor(a0, 16); a1 += __shfl_xor(a1, 16);
  a2 += __shfl_xor(a2, 16); a3 += __shfl_xor(a3, 16);
  a4 += __shfl_xor(a4, 16); a5 += __shfl_xor(a5, 16);
  a6 += __shfl_xor(a6, 16); a7 += __shfl_xor(a7, 16);
  a0 += __shfl_xor(a0, 32); a1 += __shfl_xor(a1, 32);
  a2 += __shfl_xor(a2, 32); a3 += __shfl_xor(a3, 32);
  a4 += __shfl_xor(a4, 32); a5 += __shfl_xor(a5, 32);
  a6 += __shfl_xor(a6, 32); a7 += __shfl_xor(a7, 32);
  if (grp == 0){
    uint4 o;
    o.x = pk2(a0*dn, a1*dn);
    o.y = pk2(a2*dn, a3*dn);
    o.z = pk2(a4*dn, a5*dn);
    o.w = pk2(a6*dn, a7*dn);
    *reinterpret_cast<uint4*>(Agg + node*128 + q8) = o;
  }
}

// MFMA GEMM: Cout = bf16(relu(bn((X @ W^T) + bias))). No Jk (JK folded into k_final).
// 256 thr = 4 waves x 16 rows (BM=64); LDS-bounce epilogue -> coalesced uint4 stores.
template<int MODE>   // 1: X fp32; 2: X bf16
__global__ __launch_bounds__(256)
void k_mm(const float* __restrict__ Xf, const unsigned short* __restrict__ Xb,
          const unsigned short* __restrict__ Wf, const float* __restrict__ bias,
          const float* __restrict__ gamma, const float* __restrict__ beta,
          unsigned short* __restrict__ Cout){
  __shared__ uint4 Ws4[2048];                       // 32KB: weights, then epilogue bounce
  unsigned short* Ws = (unsigned short*)Ws4;
  const int t = threadIdx.x;
  {
    const uint4* src = reinterpret_cast<const uint4*>(Wf);
    #pragma unroll
    for (int i = 0; i < 8; ++i) Ws4[i*256 + t] = src[i*256 + t];
  }
  const int lane = t & 63;
  const int wv = t >> 6;
  const int m0 = blockIdx.x*64 + wv*16;
  const int mrow = min(m0 + (lane & 15), NN-1);
  const int kg = (lane >> 4)*8;
  bf16x8 a[4];
  if constexpr (MODE == 1){
    const float* px = Xf + (size_t)mrow*128 + kg;
    #pragma unroll
    for (int ks = 0; ks < 4; ++ks){
      float4 f0 = ld4(px + ks*32);
      float4 f1 = ld4(px + ks*32 + 4);
      bf16x8 aa;
      aa[0]=(__bf16)f0.x; aa[1]=(__bf16)f0.y; aa[2]=(__bf16)f0.z; aa[3]=(__bf16)f0.w;
      aa[4]=(__bf16)f1.x; aa[5]=(__bf16)f1.y; aa[6]=(__bf16)f1.z; aa[7]=(__bf16)f1.w;
      a[ks] = aa;
    }
  } else {
    const unsigned short* px = Xb + (size_t)mrow*128 + kg;
    #pragma unroll
    for (int ks = 0; ks < 4; ++ks)
      a[ks] = *reinterpret_cast<const bf16x8*>(px + ks*32);
  }
  __syncthreads();
  f32x4 acc[8];
  #pragma unroll
  for (int nt = 0; nt < 8; ++nt) acc[nt] = (f32x4){0.f,0.f,0.f,0.f};
  #pragma unroll
  for (int ks = 0; ks < 4; ++ks){
    #pragma unroll
    for (int nt = 0; nt < 8; ++nt){
      bf16x8 bfr = *reinterpret_cast<const bf16x8*>(Ws + ((nt*4 + ks)*64 + lane)*8);
      acc[nt] = __builtin_amdgcn_mfma_f32_16x16x32_bf16(a[ks], bfr, acc[nt], 0, 0, 0);
    }
  }
  // ---- epilogue: bn+relu -> bf16 -> LDS [wv][16 rows][136 pad] -> coalesced stores
  __syncthreads();                                  // weights no longer needed
  const int cB = lane & 15;
  const int r0 = (lane >> 4)*4;
  unsigned short* eld = Ws + wv*2176;               // 16*136 u16 per wave
  #pragma unroll
  for (int nt = 0; nt < 8; ++nt){
    int cb = nt*16 + cB;
    float bi = bias[cb];
    float g  = gamma[cb]*BN_SC;
    float be = beta[cb];
    #pragma unroll
    for (int r = 0; r < 4; ++r){
      float o = fmaxf(fmaf(acc[nt][r] + bi, g, be), 0.f);
      eld[(r0 + r)*136 + cb] = f2bf(o);
    }
  }
  __syncthreads();
  {
    int lrow = t >> 2, seg = t & 3;                 // 64 rows x 4 segments of 64B
    int grow = blockIdx.x*64 + lrow;
    if (grow < NN){
      const unsigned short* src = Ws + (lrow >> 4)*2176 + (lrow & 15)*136 + seg*32;
      uint4* dst = reinterpret_cast<uint4*>(Cout + (size_t)grow*128 + seg*32);
      #pragma unroll
      for (int j = 0; j < 4; ++j) dst[j] = *reinterpret_cast<const uint4*>(src + j*8);
    }
  }
}

// Final MFMA GEMM: Out[m][c] = max(H0,H1,H2)[m] . Wf[c] + bf[c], C=40 (padded 48).
__global__ __launch_bounds__(256)
void k_final(const unsigned short* __restrict__ H0, const unsigned short* __restrict__ H1,
             const unsigned short* __restrict__ H2, const unsigned short* __restrict__ Wff,
             const float* __restrict__ bfv, float* __restrict__ Out){
  const int t = threadIdx.x;
  const int lane = t & 63;
  const int wv = t >> 6;
  const int m0 = blockIdx.x*64 + wv*16;
  const int mrow = min(m0 + (lane & 15), NN-1);
  const int kg = (lane >> 4)*8;
  bf16x8 a[4];
  const size_t pbase = (size_t)mrow*128 + kg;
  #pragma unroll
  for (int ks = 0; ks < 4; ++ks){
    union U { uint4 v; unsigned short s[8]; } u0, u1, u2, r;
    u0.v = *reinterpret_cast<const uint4*>(H0 + pbase + ks*32);
    u1.v = *reinterpret_cast<const uint4*>(H1 + pbase + ks*32);
    u2.v = *reinterpret_cast<const uint4*>(H2 + pbase + ks*32);
    #pragma unroll
    for (int j = 0; j < 8; ++j){
      unsigned short m = u0.s[j] > u1.s[j] ? u0.s[j] : u1.s[j];   // relu>=0: u16 cmp == f cmp
      r.s[j] = m > u2.s[j] ? m : u2.s[j];
    }
    a[ks] = *reinterpret_cast<bf16x8*>(&r);
  }
  bf16x8 b[3][4];
  #pragma unroll
  for (int nt = 0; nt < 3; ++nt)
    #pragma unroll
    for (int ks = 0; ks < 4; ++ks)
      b[nt][ks] = *reinterpret_cast<const bf16x8*>(Wff + ((nt*4 + ks)*64 + lane)*8);
  f32x4 acc[3];
  #pragma unroll
  for (int nt = 0; nt < 3; ++nt) acc[nt] = (f32x4){0.f,0.f,0.f,0.f};
  #pragma unroll
  for (int ks = 0; ks < 4; ++ks)
    #pragma unroll
    for (int nt = 0; nt < 3; ++nt)
      acc[nt] = __builtin_amdgcn_mfma_f32_16x16x32_bf16(a[ks], b[nt][ks], acc[nt], 0, 0, 0);
  const int cB = lane & 15;
  const int r0 = (lane >> 4)*4;
  #pragma unroll
  for (int nt = 0; nt < 3; ++nt){
    int cb = nt*16 + cB;
    if (cb < 40){
      float bi = bfv[cb];
      #pragma unroll
      for (int r = 0; r < 4; ++r){
        int row = m0 + r0 + r;
        if (row < NN) Out[(size_t)row*40 + cb] = acc[nt][r] + bi;
      }
    }
  }
}

extern "C" void kernel_launch(void* const* d_in, const int* in_sizes, int n_in,
                              void* d_out, int out_size, void* d_ws, size_t ws_size,
                              hipStream_t stream){
  const float* x     = (const float*)d_in[0];
  const int*   ei    = (const int*)d_in[1];
  const float* fc0_w = (const float*)d_in[2];
  const float* fc0_b = (const float*)d_in[3];
  const float* convw = (const float*)d_in[4];
  const float* Ww    = (const float*)d_in[5];
  const float* Wb    = (const float*)d_in[6];
  const float* bng   = (const float*)d_in[7];
  const float* bnb   = (const float*)d_in[8];
  const float* fow   = (const float*)d_in[9];
  const float* fob   = (const float*)d_in[10];
  const float* outw  = (const float*)d_in[11];
  const float* outb  = (const float*)d_in[12];
  float* out = (float*)d_out;

  char* p = (char*)d_ws;
  auto alloc = [&](size_t n){ char* r = p; p += (n + 255) & ~(size_t)255; return r; };
  int*   hists   = (int*)  alloc((size_t)BINBLK*NB*4);
  int*   ebase   = (int*)  alloc((size_t)(NB+1)*4);
  int*   gcur    = (int*)  alloc((size_t)NB*4);
  unsigned int*   bbuf  = (unsigned int*)  alloc((size_t)NE*4);
  unsigned short* csr16 = (unsigned short*)alloc((size_t)EN*2);
  int*   offs    = (int*)  alloc((size_t)(NN+1)*4);
  float* dis     = (float*)alloc((size_t)NN*4);
  unsigned short* W0f  = (unsigned short*)alloc(16384*2);
  unsigned short* WC0f = (unsigned short*)alloc(16384*2);
  unsigned short* WC1f = (unsigned short*)alloc(16384*2);
  unsigned short* Wff  = (unsigned short*)alloc(6144*2);
  float* bfv     = (float*)alloc(64*4);
  unsigned short* H0  = (unsigned short*)alloc((size_t)NN*128*2);
  unsigned short* H1  = (unsigned short*)alloc((size_t)NN*128*2);
  unsigned short* H2  = (unsigned short*)alloc((size_t)NN*128*2);
  unsigned short* AGG = (unsigned short*)alloc((size_t)NN*128*2);

  k_prep<<<216 + BINBLK, 256, 0, stream>>>(fc0_w, Ww, convw, outw, fow, fob, outb, ei,
                                           W0f, WC0f, WC1f, Wff, bfv, hists);
  k_bscan<<<1, 1024, 0, stream>>>(hists, ebase, gcur);
  k_bin<<<BINBLK, 256, 0, stream>>>(ei, gcur, bbuf);
  k_csr<<<NB, 256, 0, stream>>>(bbuf, ebase, csr16, offs, dis);

  k_mm<1><<<782, 256, 0, stream>>>(x, nullptr, W0f, fc0_b, bng, bnb, H0);
  k_gather<<<12500, 256, 0, stream>>>(H0, csr16, dis, offs, AGG);
  k_mm<2><<<782, 256, 0, stream>>>(nullptr, AGG, WC0f, Wb, bng + 128, bnb + 128, H1);
  k_gather<<<12500, 256, 0, stream>>>(H1, csr16, dis, offs, AGG);
  k_mm<2><<<782, 256, 0, stream>>>(nullptr, AGG, WC1f, Wb, bng + 256, bnb + 256, H2);
  k_final<<<782, 256, 0, stream>>>(H0, H1, H2, Wff, bfv, out);
}